// Round 14
// baseline (1873.837 us; speedup 1.0000x reference)
//
#include <hip/hip_runtime.h>
#include <hip/hip_cooperative_groups.h>

namespace cg = cooperative_groups;

#define NGRAPH 2048

typedef __attribute__((ext_vector_type(8))) short bf16x8;
typedef __attribute__((ext_vector_type(4))) float f32x4;
typedef __attribute__((ext_vector_type(8))) _Float16 h16x8;
typedef __attribute__((ext_vector_type(4))) _Float16 h16x4;

__device__ inline unsigned short bf16_rne(float f) {
  union { float f; unsigned u; } c; c.f = f;
  unsigned u = c.u + 0x7fffu + ((c.u >> 16) & 1u);
  return (unsigned short)(u >> 16);
}
__device__ inline float bf16_to_f32(unsigned short h) {
  union { float f; unsigned u; } c; c.u = ((unsigned)h) << 16;
  return c.f;
}

// ================= shared device functions =================

__device__ inline void mfma_pass(
    const _Float16* zbuf,
    const unsigned short* __restrict__ Whi, const unsigned short* __restrict__ Wlo,
    int rw, int m16, int quad, int lane, f32x4 acc[8])
{
  int r = rw + m16;
  const _Float16* zrow = &zbuf[r * 128];
#pragma unroll
  for (int kc = 0; kc < 4; ++kc) {
    int cidx = kc * 4 + quad;
    h16x8 zh = *(const h16x8*)&zrow[((cidx + r) & 15) * 8];
    bf16x8 ah, al;
#pragma unroll
    for (int j = 0; j < 8; ++j) {
      float f = (float)zh[j];
      unsigned short h = bf16_rne(f);
      ah[j] = (short)h;
      al[j] = (short)bf16_rne(f - bf16_to_f32(h));
    }
#pragma unroll
    for (int t = 0; t < 8; ++t) {
      long cb = ((t * 4 + kc) * 64 + lane) * 8;
      bf16x8 bh = *(const bf16x8*)&Whi[cb];
      bf16x8 bl = *(const bf16x8*)&Wlo[cb];
      acc[t] = __builtin_amdgcn_mfma_f32_16x16x32_bf16(ah, bh, acc[t], 0, 0, 0);
      acc[t] = __builtin_amdgcn_mfma_f32_16x16x32_bf16(ah, bl, acc[t], 0, 0, 0);
      acc[t] = __builtin_amdgcn_mfma_f32_16x16x32_bf16(al, bh, acc[t], 0, 0, 0);
    }
  }
}

__device__ void gin_tile(
    _Float16* zbuf, const _Float16* __restrict__ H,
    const int* __restrict__ rowstart, const int* __restrict__ eidx,
    const unsigned short* __restrict__ W1hi, const unsigned short* __restrict__ W1lo,
    const float* __restrict__ B1,
    const unsigned short* __restrict__ W2hi, const unsigned short* __restrict__ W2lo,
    const float* __restrict__ B2,
    _Float16* __restrict__ Out, int M, int tile, int tid)
{
  int rbase = tile * 64;
  {
    int sub = tid & 15;
    int ng = tid >> 4;
    const _Float16* Hc = H + sub * 8;
#pragma unroll
    for (int it = 0; it < 4; ++it) {
      int r = it * 16 + ng;
      int v = rbase + r;
      int vc = (v < M) ? v : (M - 1);
      h16x8 sv = *(const h16x8*)&Hc[(long)vc * 128];
      float a0[8], a1[8];
#pragma unroll
      for (int j = 0; j < 8; ++j) { a0[j] = (float)sv[j]; a1[j] = 0.f; }
      int e0 = rowstart[vc], e1 = rowstart[vc + 1];
      int e = e0;
      for (; e + 4 <= e1; e += 4) {
        int s0 = eidx[e], s1 = eidx[e + 1], s2 = eidx[e + 2], s3 = eidx[e + 3];
        h16x8 h0 = *(const h16x8*)&Hc[(long)s0 * 128];
        h16x8 h1 = *(const h16x8*)&Hc[(long)s1 * 128];
        h16x8 h2 = *(const h16x8*)&Hc[(long)s2 * 128];
        h16x8 h3 = *(const h16x8*)&Hc[(long)s3 * 128];
#pragma unroll
        for (int j = 0; j < 8; ++j) {
          a0[j] += (float)h0[j] + (float)h2[j];
          a1[j] += (float)h1[j] + (float)h3[j];
        }
      }
      for (; e < e1; ++e) {
        int s = eidx[e];
        h16x8 h = *(const h16x8*)&Hc[(long)s * 128];
#pragma unroll
        for (int j = 0; j < 8; ++j) a1[j] += (float)h[j];
      }
      h16x8 zo;
#pragma unroll
      for (int j = 0; j < 8; ++j) zo[j] = (_Float16)(a0[j] + a1[j]);
      *(h16x8*)&zbuf[r * 128 + ((sub + r) & 15) * 8] = zo;
    }
  }
  __syncthreads();

  int lane = tid & 63;
  int wv = tid >> 6;
  int m16 = lane & 15;
  int quad = lane >> 4;
  int rw = wv * 16;

  f32x4 acc[8];
#pragma unroll
  for (int t = 0; t < 8; ++t) acc[t] = (f32x4){0.f, 0.f, 0.f, 0.f};
  mfma_pass(zbuf, W1hi, W1lo, rw, m16, quad, lane, acc);

  float bias[8];
#pragma unroll
  for (int t = 0; t < 8; ++t) bias[t] = B1[t * 16 + m16];

  __syncthreads();
#pragma unroll
  for (int i = 0; i < 4; ++i) {
    int r = rw + quad * 4 + i;
#pragma unroll
    for (int t = 0; t < 8; ++t) {
      int col = t * 16 + m16;
      int cidx = col >> 3;
      zbuf[r * 128 + ((cidx + r) & 15) * 8 + (col & 7)] =
          (_Float16)fmaxf(acc[t][i] + bias[t], 0.f);
    }
  }
  __syncthreads();

#pragma unroll
  for (int t = 0; t < 8; ++t) acc[t] = (f32x4){0.f, 0.f, 0.f, 0.f};
  mfma_pass(zbuf, W2hi, W2lo, rw, m16, quad, lane, acc);

#pragma unroll
  for (int t = 0; t < 8; ++t) bias[t] = B2[t * 16 + m16];

#pragma unroll
  for (int i = 0; i < 4; ++i) {
    int r = rbase + rw + quad * 4 + i;
    if (r < M) {
#pragma unroll
      for (int t = 0; t < 8; ++t) {
        float o = fmaxf(acc[t][i] + bias[t], 0.f);
        Out[(long)r * 128 + t * 16 + m16] = (_Float16)o;
      }
    }
  }
  __syncthreads();
}

__device__ void l1_tile(
    _Float16* ybuf, float (*z1s)[8],
    const float* __restrict__ x8, const int* __restrict__ rowstart,
    const int* __restrict__ eidx,
    const float* __restrict__ W1, const float* __restrict__ B1,
    const unsigned short* __restrict__ W2hi, const unsigned short* __restrict__ W2lo,
    const float* __restrict__ B2, _Float16* __restrict__ Out, int M, int tile, int tid)
{
  int rbase = tile * 64;
  {
    int node = tid >> 2, sub = tid & 3;
    int c = (sub & 1) * 4, par = sub >> 1;
    int v = rbase + node;
    int vc = (v < M) ? v : (M - 1);
    const float* Xc = x8 + c;
    float4 a = {0.f, 0.f, 0.f, 0.f};
    float4 a1 = {0.f, 0.f, 0.f, 0.f};
    if (!par) a = *(const float4*)&Xc[(long)vc * 8];
    int e0 = rowstart[vc], e1 = rowstart[vc + 1];
    int e = e0 + par;
    for (; e + 2 < e1; e += 4) {
      int s0 = eidx[e], s1 = eidx[e + 2];
      float4 h0 = *(const float4*)&Xc[(long)s0 * 8];
      float4 h1 = *(const float4*)&Xc[(long)s1 * 8];
      a.x += h0.x; a.y += h0.y; a.z += h0.z; a.w += h0.w;
      a1.x += h1.x; a1.y += h1.y; a1.z += h1.z; a1.w += h1.w;
    }
    for (; e < e1; e += 2) {
      int s = eidx[e];
      float4 h = *(const float4*)&Xc[(long)s * 8];
      a.x += h.x; a.y += h.y; a.z += h.z; a.w += h.w;
    }
    a.x += a1.x; a.y += a1.y; a.z += a1.z; a.w += a1.w;
    if (par) *(float4*)&z1s[node][c] = a;
    __syncthreads();
    if (!par) {
      float4 b = *(const float4*)&z1s[node][c];
      a.x += b.x; a.y += b.y; a.z += b.z; a.w += b.w;
      *(float4*)&z1s[node][c] = a;
    }
  }
  __syncthreads();

  {
    int c = tid & 127;
    int cidx = c >> 3, celt = c & 7;
    int rh0 = (tid >> 7) * 32;
    float w1r[7];
#pragma unroll
    for (int k = 0; k < 7; ++k) w1r[k] = W1[k * 128 + c];
    float b1 = B1[c];
#pragma unroll 4
    for (int rr = 0; rr < 32; ++rr) {
      int r = rh0 + rr;
      const float* zp = z1s[r];
      float a = b1;
#pragma unroll
      for (int k = 0; k < 7; ++k) a += zp[k] * w1r[k];
      ybuf[r * 128 + ((cidx + r) & 15) * 8 + celt] = (_Float16)fmaxf(a, 0.f);
    }
  }
  __syncthreads();

  int lane = tid & 63;
  int wv = tid >> 6;
  int m16 = lane & 15;
  int quad = lane >> 4;
  int rw = wv * 16;

  f32x4 acc[8];
#pragma unroll
  for (int t = 0; t < 8; ++t) acc[t] = (f32x4){0.f, 0.f, 0.f, 0.f};
  mfma_pass(ybuf, W2hi, W2lo, rw, m16, quad, lane, acc);

  float bias[8];
#pragma unroll
  for (int t = 0; t < 8; ++t) bias[t] = B2[t * 16 + m16];

#pragma unroll
  for (int i = 0; i < 4; ++i) {
    int r = rbase + rw + quad * 4 + i;
    if (r < M) {
#pragma unroll
      for (int t = 0; t < 8; ++t) {
        float o = fmaxf(acc[t][i] + bias[t], 0.f);
        Out[(long)r * 128 + t * 16 + m16] = (_Float16)o;
      }
    }
  }
  __syncthreads();
}

__device__ void pool_item(
    long gt, const _Float16* __restrict__ H, const int* __restrict__ batch,
    float* __restrict__ P, float* __restrict__ cnt, int Nn, int colOff, bool doCnt)
{
  int cgp = (int)(gt & 31);
  int chunk = (int)(gt >> 5);
  int i0 = chunk * 16;
  if (i0 >= Nn) return;
  int c = cgp * 4;
  float4 acc = {0.f, 0.f, 0.f, 0.f};
  int curb = -1;
  float runc = 0.f;
  for (int ii = 0; ii < 16; ++ii) {
    int i = i0 + ii;
    if (i >= Nn) break;
    int b = batch[i];
    if (b != curb) {
      if (curb >= 0) {
        float* p = &P[(long)curb * 384 + colOff + c];
        atomicAdd(p + 0, acc.x); atomicAdd(p + 1, acc.y);
        atomicAdd(p + 2, acc.z); atomicAdd(p + 3, acc.w);
        if (doCnt && cgp == 0) atomicAdd(&cnt[curb], runc);
      }
      acc.x = acc.y = acc.z = acc.w = 0.f;
      runc = 0.f;
      curb = b;
    }
    h16x4 v = *(const h16x4*)&H[(long)i * 128 + c];
    acc.x += (float)v[0]; acc.y += (float)v[1]; acc.z += (float)v[2]; acc.w += (float)v[3];
    runc += 1.f;
  }
  if (curb >= 0) {
    float* p = &P[(long)curb * 384 + colOff + c];
    atomicAdd(p + 0, acc.x); atomicAdd(p + 1, acc.y);
    atomicAdd(p + 2, acc.z); atomicAdd(p + 3, acc.w);
    if (doCnt && cgp == 0) atomicAdd(&cnt[curb], runc);
  }
}

struct MP {
  const float* x;
  const int* src; const int* dst; const int* batch;
  const float* g1w1; const float* g1b1;
  const float* wsrc[5];
  const float* bias[5];
  const float* jkw; const float* jkb;
  const float* c1w; const float* c1b;
  const float* bng; const float* bnb;
  const float* c2w; const float* c2b;
  _Float16* hA; _Float16* hB;
  float* x8;
  float* P; float* cnt; float* bnstat;
  float* zc; float* gbuf;
  int* deg; int* cursor; int* rowstart; int* bsum; int* eidx;
  unsigned short* whi[5]; unsigned short* wlo[5];
  float* out;
  int N, E, nTiles;
};

// ================= mega-kernel: grid-strided stages, 1024 persistent blocks =================
__global__ __launch_bounds__(256, 4) void mega(MP p)
{
  cg::grid_group grid = cg::this_grid();
  __shared__ alignas(16) char smem[18432];
  _Float16* zbuf = (_Float16*)smem;
  float (*z1s)[8] = (float(*)[8])(smem + 16384);
  int tid = threadIdx.x, blk = blockIdx.x;
  int nblk = gridDim.x;
  long stride = (long)nblk * 256;
  long gt = (long)blk * 256 + tid;
  const int N = p.N, E = p.E;
  const int nchunk = (N + 255) >> 8;
  const long poolItems = (long)((N + 15) >> 4) * 32;

  // Z: zero + weight repack + x pad
  for (long i = gt; i < N; i += stride) { p.deg[i] = 0; p.cursor[i] = 0; }
  for (long i = gt; i < (long)NGRAPH * 384; i += stride) p.P[i] = 0.f;
  if (gt < NGRAPH) p.cnt[gt] = 0.f;
  if (gt < 256) p.bnstat[gt] = 0.f;
  for (long q = gt; q < 5 * 16384; q += stride) {
    int m = (int)(q >> 14);
    int j = (int)(q & 16383);
    int c = j >> 3, e = j & 7;
    int t = c >> 8, kc = (c >> 6) & 3, lane = c & 63;
    int n = t * 16 + (lane & 15);
    int k = kc * 32 + (lane >> 4) * 8 + e;
    float w = p.wsrc[m][k * 128 + n];
    unsigned short h = bf16_rne(w);
    p.whi[m][j] = h;
    p.wlo[m][j] = bf16_rne(w - bf16_to_f32(h));
  }
  for (long i = gt; i < (long)N * 8; i += stride) {
    int v = (int)(i >> 3), j = (int)(i & 7);
    p.x8[i] = (j < 7) ? p.x[(long)v * 7 + j] : 0.f;
  }
  grid.sync();

  // A: degree histogram
  for (long e = gt; e < E; e += stride) atomicAdd(&p.deg[p.dst[e]], 1);
  grid.sync();

  // S1: per-chunk scan
  for (int cb = blk; cb < nchunk; cb += nblk) {
    int* tmp = (int*)smem;
    int i = cb * 256 + tid;
    int v = (i < N) ? p.deg[i] : 0;
    tmp[tid] = v;
    __syncthreads();
#pragma unroll
    for (int off = 1; off < 256; off <<= 1) {
      int t2 = (tid >= off) ? tmp[tid - off] : 0;
      __syncthreads();
      tmp[tid] += t2;
      __syncthreads();
    }
    if (i < N) p.rowstart[i] = tmp[tid] - v;
    if (tid == 255) p.bsum[cb] = tmp[255];
    __syncthreads();
  }
  grid.sync();

  // S2: scan chunk sums (block 0 only)
  if (blk == 0) {
    int* tmp = (int*)smem;
    for (int i = tid; i < nchunk; i += 256) tmp[i] = p.bsum[i];
    __syncthreads();
    if (tid == 0) {
      int run = 0;
      for (int i = 0; i < nchunk; ++i) { int v = tmp[i]; tmp[i] = run; run += v; }
      p.rowstart[N] = E;
    }
    __syncthreads();
    for (int i = tid; i < nchunk; i += 256) p.bsum[i] = tmp[i];
  }
  grid.sync();

  // S3: add chunk offsets
  for (long i = gt; i < N; i += stride) p.rowstart[i] += p.bsum[i >> 8];
  grid.sync();

  // C: fill eidx
  for (long e = gt; e < E; e += stride) {
    int d = p.dst[e];
    int pos = p.rowstart[d] + atomicAdd(&p.cursor[d], 1);
    p.eidx[pos] = p.src[e];
  }
  grid.sync();

  // L1
  for (int tile = blk; tile < p.nTiles; tile += nblk)
    l1_tile(zbuf, z1s, p.x8, p.rowstart, p.eidx, p.g1w1, p.g1b1,
            p.whi[0], p.wlo[0], p.bias[0], p.hA, N, tile, tid);
  grid.sync();

  // E: layer 2 + pool1
  for (int tile = blk; tile < p.nTiles; tile += nblk)
    gin_tile(zbuf, p.hA, p.rowstart, p.eidx, p.whi[1], p.wlo[1], p.bias[1],
             p.whi[2], p.wlo[2], p.bias[2], p.hB, N, tile, tid);
  for (long it = gt; it < poolItems; it += stride)
    pool_item(it, p.hA, p.batch, p.P, p.cnt, N, 0, true);
  grid.sync();

  // F: layer 3 + pool2
  for (int tile = blk; tile < p.nTiles; tile += nblk)
    gin_tile(zbuf, p.hB, p.rowstart, p.eidx, p.whi[3], p.wlo[3], p.bias[3],
             p.whi[4], p.wlo[4], p.bias[4], p.hA, N, tile, tid);
  for (long it = gt; it < poolItems; it += stride)
    pool_item(it, p.hB, p.batch, p.P, p.cnt, N, 128, false);
  grid.sync();

  // G: pool3
  for (long it = gt; it < poolItems; it += stride)
    pool_item(it, p.hA, p.batch, p.P, p.cnt, N, 256, false);
  grid.sync();

  // H: head — jk + classifier + BN stats
  for (int rp = blk; rp < NGRAPH / 2; rp += nblk) {
    float* pl = (float*)smem;
    float* G2 = pl + 768;
    float* zs = G2 + 256;
    int row0 = rp * 2;
    for (int o = tid; o < 768; o += 256) pl[o] = p.P[(long)row0 * 384 + o];
    __syncthreads();
    int rr = tid >> 7, col = tid & 127;
    int row = row0 + rr;
    float acc = p.cnt[row] * p.jkb[col];
#pragma unroll 8
    for (int k = 0; k < 384; ++k) acc += pl[rr * 384 + k] * p.jkw[k * 128 + col];
    G2[rr * 128 + col] = acc;
    __syncthreads();
    float a2 = p.c1b[col];
#pragma unroll 4
    for (int k = 0; k < 128; ++k) a2 += G2[rr * 128 + k] * p.c1w[k * 128 + col];
    p.zc[(long)row * 128 + col] = a2;
    zs[rr * 128 + col] = a2;
    __syncthreads();
    if (rr == 0) {
      float v0 = zs[col], v1 = zs[128 + col];
      atomicAdd(&p.bnstat[col], v0 + v1);
      atomicAdd(&p.bnstat[128 + col], v0 * v0 + v1 * v1);
    }
    __syncthreads();
  }
  grid.sync();

  // I: BN + relu + final matmul
  for (int gb = blk; gb < (NGRAPH + 255) / 256; gb += nblk) {
    float* scl = (float*)smem;
    float* shf = scl + 128;
    if (tid < 128) {
      float mu = p.bnstat[tid] * (1.f / NGRAPH);
      float var = p.bnstat[128 + tid] * (1.f / NGRAPH) - mu * mu;
      float rs = rsqrtf(var + 1e-5f);
      float sc = p.bng[tid] * rs;
      scl[tid] = sc;
      shf[tid] = p.bnb[tid] - mu * sc;
    }
    __syncthreads();
    int g = gb * 256 + tid;
    if (g < NGRAPH) {
      float a0 = p.c2b[0], a1 = p.c2b[1];
#pragma unroll 4
      for (int h = 0; h < 128; ++h) {
        float zn = p.zc[(long)g * 128 + h] * scl[h] + shf[h];
        zn = fmaxf(zn, 0.f);
        a0 += zn * p.c2w[2 * h];
        a1 += zn * p.c2w[2 * h + 1];
      }
      p.out[2 * g] = a0;
      p.out[2 * g + 1] = a1;
    }
    __syncthreads();
  }
}

// ================= fallback standalone kernels (R12 pipeline) =================

__global__ __launch_bounds__(256) void scan1(
    const int* __restrict__ deg, int* __restrict__ rowstart, int* __restrict__ bsum, int N)
{
  __shared__ int tmp[256];
  int i = blockIdx.x * 256 + threadIdx.x;
  int v = (i < N) ? deg[i] : 0;
  tmp[threadIdx.x] = v;
  __syncthreads();
#pragma unroll
  for (int off = 1; off < 256; off <<= 1) {
    int t = (threadIdx.x >= (unsigned)off) ? tmp[threadIdx.x - off] : 0;
    __syncthreads();
    tmp[threadIdx.x] += t;
    __syncthreads();
  }
  if (i < N) rowstart[i] = tmp[threadIdx.x] - v;
  if (threadIdx.x == 255) bsum[blockIdx.x] = tmp[255];
}

__global__ __launch_bounds__(1024) void scan2(
    int* __restrict__ bsum, int nb, int* __restrict__ rowstart, int N, int E)
{
  __shared__ int tmp[1024];
  int i = threadIdx.x;
  int v = (i < nb) ? bsum[i] : 0;
  tmp[i] = v;
  __syncthreads();
#pragma unroll
  for (int off = 1; off < 1024; off <<= 1) {
    int t = (i >= off) ? tmp[i - off] : 0;
    __syncthreads();
    tmp[i] += t;
    __syncthreads();
  }
  if (i < nb) bsum[i] = tmp[i] - v;
  if (i == 0) rowstart[N] = E;
}

__global__ __launch_bounds__(256) void scan3(
    int* __restrict__ rowstart, const int* __restrict__ bsum, int N)
{
  int i = blockIdx.x * 256 + threadIdx.x;
  if (i < N) rowstart[i] += bsum[blockIdx.x];
}

__global__ __launch_bounds__(256) void fill_eidx_k(
    const int* __restrict__ src, const int* __restrict__ dst,
    const int* __restrict__ rowstart, int* __restrict__ cursor,
    int* __restrict__ eidx, int E)
{
  int e = blockIdx.x * 256 + threadIdx.x;
  if (e >= E) return;
  int d = dst[e];
  int pos = rowstart[d] + atomicAdd(&cursor[d], 1);
  eidx[pos] = src[e];
}

struct WPs {
  const float* w[5];
  unsigned short* hi[5];
  unsigned short* lo[5];
};
__global__ __launch_bounds__(256) void prep_hist(
    WPs p, const float* __restrict__ x, float* __restrict__ x8, int N,
    const int* __restrict__ dst, int* __restrict__ deg, int E)
{
  int g = blockIdx.x * 256 + threadIdx.x;
  if (g < E) {
    atomicAdd(&deg[dst[g]], 1);
    return;
  }
  int q = g - E;
  if (q < 5 * 16384) {
    int m = q >> 14;
    int j = q & 16383;
    int c = j >> 3, e = j & 7;
    int t = c >> 8, kc = (c >> 6) & 3, lane = c & 63;
    int n = t * 16 + (lane & 15);
    int k = kc * 32 + (lane >> 4) * 8 + e;
    float w = p.w[m][k * 128 + n];
    unsigned short h = bf16_rne(w);
    p.hi[m][j] = h;
    p.lo[m][j] = bf16_rne(w - bf16_to_f32(h));
  } else {
    int i = q - 5 * 16384;
    if (i < N * 8) {
      int v = i >> 3, j = i & 7;
      x8[i] = (j < 7) ? x[v * 7 + j] : 0.f;
    }
  }
}

__global__ __launch_bounds__(256, 8) void fused_gin_k(
    const _Float16* __restrict__ H, const int* __restrict__ rowstart,
    const int* __restrict__ eidx,
    const unsigned short* __restrict__ W1hi, const unsigned short* __restrict__ W1lo,
    const float* __restrict__ B1,
    const unsigned short* __restrict__ W2hi, const unsigned short* __restrict__ W2lo,
    const float* __restrict__ B2, _Float16* __restrict__ Out, int M)
{
  __shared__ _Float16 zbuf[64 * 128];
  gin_tile(zbuf, H, rowstart, eidx, W1hi, W1lo, B1, W2hi, W2lo, B2, Out, M,
           blockIdx.x, threadIdx.x);
}

__global__ __launch_bounds__(256, 8) void fused_l1_k(
    const float* __restrict__ x8, const int* __restrict__ rowstart,
    const int* __restrict__ eidx,
    const float* __restrict__ W1, const float* __restrict__ B1,
    const unsigned short* __restrict__ W2hi, const unsigned short* __restrict__ W2lo,
    const float* __restrict__ B2, _Float16* __restrict__ Out, int M)
{
  __shared__ _Float16 ybuf[64 * 128];
  __shared__ float z1s[64][8];
  l1_tile(ybuf, z1s, x8, rowstart, eidx, W1, B1, W2hi, W2lo, B2, Out, M,
          blockIdx.x, threadIdx.x);
}

template <bool DO_CNT>
__global__ __launch_bounds__(256) void pool128(
    const _Float16* __restrict__ H, const int* __restrict__ batch,
    float* __restrict__ P, float* __restrict__ cnt, int Nn, int colOff)
{
  long gt = (long)blockIdx.x * 256 + threadIdx.x;
  pool_item(gt, H, batch, P, cnt, Nn, colOff, DO_CNT);
}

__global__ __launch_bounds__(256) void jk_gemm(
    const float* __restrict__ P, const float* __restrict__ cnt,
    const float* __restrict__ W, const float* __restrict__ B,
    float* __restrict__ G)
{
  __shared__ float pl[768];
  int tid = threadIdx.x, blk = blockIdx.x;
  for (int o = tid; o < 768; o += 256) pl[o] = P[(long)blk * 768 + o];
  __syncthreads();
  int rr = tid >> 7;
  int col = tid & 127;
  int row = blk * 2 + rr;
  float acc = cnt[row] * B[col];
#pragma unroll 8
  for (int k = 0; k < 384; ++k)
    acc += pl[rr * 384 + k] * W[k * 128 + col];
  G[(long)row * 128 + col] = acc;
}

__global__ __launch_bounds__(256) void gemm_bn(
    const float* __restrict__ Z,
    const float* __restrict__ W, const float* __restrict__ B,
    float* __restrict__ Out, float* __restrict__ bnstat, int M)
{
  __shared__ float wlds[128 * 128];
  int tid = threadIdx.x;
  {
    const float4* Ws = (const float4*)W;
    float4* Wd = (float4*)wlds;
#pragma unroll
    for (int i = 0; i < 16; ++i) Wd[i * 256 + tid] = Ws[i * 256 + tid];
  }
  __syncthreads();

  int rg = tid >> 5;
  int c0 = (tid & 31) * 4;
  int rbase = blockIdx.x * 64 + rg * 8;

  float acc[8][4];
#pragma unroll
  for (int i = 0; i < 8; ++i)
#pragma unroll
    for (int j = 0; j < 4; ++j) acc[i][j] = 0.f;

#pragma unroll 2
  for (int kc = 0; kc < 128; kc += 4) {
    float zv[8][4];
#pragma unroll
    for (int i = 0; i < 8; ++i) {
      float4 z = *(const float4*)&Z[(long)(rbase + i) * 128 + kc];
      zv[i][0] = z.x; zv[i][1] = z.y; zv[i][2] = z.z; zv[i][3] = z.w;
    }
#pragma unroll
    for (int kk = 0; kk < 4; ++kk) {
      float4 w = *(const float4*)&wlds[(kc + kk) * 128 + c0];
#pragma unroll
      for (int i = 0; i < 8; ++i) {
        float z = zv[i][kk];
        acc[i][0] += z * w.x; acc[i][1] += z * w.y;
        acc[i][2] += z * w.z; acc[i][3] += z * w.w;
      }
    }
  }

  float4 b = *(const float4*)&B[c0];
  float s[4] = {0.f, 0.f, 0.f, 0.f};
  float s2[4] = {0.f, 0.f, 0.f, 0.f};
#pragma unroll
  for (int i = 0; i < 8; ++i) {
    float4 o;
    o.x = acc[i][0] + b.x; o.y = acc[i][1] + b.y;
    o.z = acc[i][2] + b.z; o.w = acc[i][3] + b.w;
    *(float4*)&Out[(long)(rbase + i) * 128 + c0] = o;
    s[0] += o.x; s[1] += o.y; s[2] += o.z; s[3] += o.w;
    s2[0] += o.x * o.x; s2[1] += o.y * o.y; s2[2] += o.z * o.z; s2[3] += o.w * o.w;
  }
#pragma unroll
  for (int j = 0; j < 4; ++j) {
    atomicAdd(&bnstat[c0 + j], s[j]);
    atomicAdd(&bnstat[128 + c0 + j], s2[j]);
  }
}

__global__ __launch_bounds__(256) void bn_final(
    const float* __restrict__ ZC, const float* __restrict__ bnstat,
    const float* __restrict__ gma, const float* __restrict__ bta,
    const float* __restrict__ W2, const float* __restrict__ B2, float* __restrict__ out)
{
  __shared__ float scl[128], shf[128];
  int tid = threadIdx.x;
  if (tid < 128) {
    float mu = bnstat[tid] * (1.f / NGRAPH);
    float var = bnstat[128 + tid] * (1.f / NGRAPH) - mu * mu;
    float rs = rsqrtf(var + 1e-5f);
    float sc = gma[tid] * rs;
    scl[tid] = sc;
    shf[tid] = bta[tid] - mu * sc;
  }
  __syncthreads();
  int g = blockIdx.x * 256 + tid;
  if (g >= NGRAPH) return;
  float a0 = B2[0], a1 = B2[1];
#pragma unroll 4
  for (int h = 0; h < 128; ++h) {
    float zn = ZC[(long)g * 128 + h] * scl[h] + shf[h];
    zn = fmaxf(zn, 0.f);
    a0 += zn * W2[2 * h];
    a1 += zn * W2[2 * h + 1];
  }
  out[2 * g] = a0;
  out[2 * g + 1] = a1;
}

extern "C" void kernel_launch(void* const* d_in, const int* in_sizes, int n_in,
                              void* d_out, int out_size, void* d_ws, size_t ws_size,
                              hipStream_t stream)
{
  MP p;
  p.x     = (const float*)d_in[0];
  const int* ei = (const int*)d_in[1];
  p.batch = (const int*)d_in[3];
  p.g1w1  = (const float*)d_in[4];  p.g1b1 = (const float*)d_in[5];
  p.wsrc[0] = (const float*)d_in[6];  p.bias[0] = (const float*)d_in[7];
  p.wsrc[1] = (const float*)d_in[8];  p.bias[1] = (const float*)d_in[9];
  p.wsrc[2] = (const float*)d_in[10]; p.bias[2] = (const float*)d_in[11];
  p.wsrc[3] = (const float*)d_in[12]; p.bias[3] = (const float*)d_in[13];
  p.wsrc[4] = (const float*)d_in[14]; p.bias[4] = (const float*)d_in[15];
  p.jkw = (const float*)d_in[16]; p.jkb = (const float*)d_in[17];
  p.c1w = (const float*)d_in[18]; p.c1b = (const float*)d_in[19];
  p.bng = (const float*)d_in[20]; p.bnb = (const float*)d_in[21];
  p.c2w = (const float*)d_in[22]; p.c2b = (const float*)d_in[23];

  p.N = in_sizes[3];
  p.E = in_sizes[1] / 2;
  p.src = ei;
  p.dst = ei + p.E;
  p.nTiles = (p.N + 63) / 64;
  p.out = (float*)d_out;

  char* w = (char*)d_ws;
  auto alloc = [&](size_t bytes) {
    char* ptr = w;
    w += (bytes + 255) & ~(size_t)255;
    return ptr;
  };
  p.hA = (_Float16*)alloc((size_t)p.N * 128 * 2);
  p.hB = (_Float16*)alloc((size_t)p.N * 128 * 2);
  p.x8 = (float*)alloc((size_t)p.N * 8 * 4);
  p.P  = (float*)alloc((size_t)NGRAPH * 384 * 4);
  p.cnt = (float*)alloc((size_t)NGRAPH * 4);
  p.bnstat = (float*)alloc(256 * 4);
  p.zc = (float*)alloc((size_t)NGRAPH * 128 * 4);
  p.gbuf = (float*)alloc((size_t)NGRAPH * 128 * 4);
  p.deg = (int*)alloc((size_t)p.N * 4);
  p.cursor = (int*)alloc((size_t)p.N * 4);
  p.rowstart = (int*)alloc((size_t)(p.N + 1) * 4);
  p.bsum = (int*)alloc((size_t)1024 * 4);
  p.eidx = (int*)alloc((size_t)p.E * 4);
  unsigned short* wtbuf = (unsigned short*)alloc((size_t)5 * 2 * 16384 * 2);
  for (int m = 0; m < 5; ++m) {
    p.whi[m] = wtbuf + (size_t)m * 2 * 16384;
    p.wlo[m] = p.whi[m] + 16384;
  }

  // ---- try single cooperative mega-kernel (1024 persistent blocks) ----
  void* args[] = { &p };
  hipError_t err = hipLaunchCooperativeKernel((const void*)mega, dim3(1024), dim3(256),
                                              args, 0, stream);
  if (err == hipSuccess) return;
  (void)hipGetLastError();   // clear; run proven fallback pipeline

  const int N = p.N, E = p.E;
  const int nb = (N + 255) / 256;
  const int eb = (E + 255) / 256;
  const size_t npad = ((size_t)N * 4 + 255) & ~(size_t)255;

  hipMemsetAsync(p.deg, 0, npad + (size_t)N * 4, stream);
  hipMemsetAsync(p.P, 0, (size_t)NGRAPH * 384 * 4 + (size_t)NGRAPH * 4 + 1024, stream);

  {
    WPs wp;
    for (int m = 0; m < 5; ++m) { wp.w[m] = p.wsrc[m]; wp.hi[m] = p.whi[m]; wp.lo[m] = p.wlo[m]; }
    int total = E + 5 * 16384 + N * 8;
    prep_hist<<<(total + 255) / 256, 256, 0, stream>>>(wp, p.x, p.x8, N, p.dst, p.deg, E);
  }
  scan1<<<nb, 256, 0, stream>>>(p.deg, p.rowstart, p.bsum, N);
  scan2<<<1, 1024, 0, stream>>>(p.bsum, nb, p.rowstart, N, E);
  scan3<<<nb, 256, 0, stream>>>(p.rowstart, p.bsum, N);
  fill_eidx_k<<<eb, 256, 0, stream>>>(p.src, p.dst, p.rowstart, p.cursor, p.eidx, E);

  const int fBlocks = p.nTiles;
  const int poolBlocks = (((N + 15) / 16) * 32 + 255) / 256;

  fused_l1_k<<<fBlocks, 256, 0, stream>>>(p.x8, p.rowstart, p.eidx, p.g1w1, p.g1b1,
      p.whi[0], p.wlo[0], p.bias[0], p.hA, N);
  pool128<true><<<poolBlocks, 256, 0, stream>>>(p.hA, p.batch, p.P, p.cnt, N, 0);

  fused_gin_k<<<fBlocks, 256, 0, stream>>>(p.hA, p.rowstart, p.eidx,
      p.whi[1], p.wlo[1], p.bias[1], p.whi[2], p.wlo[2], p.bias[2], p.hB, N);
  pool128<false><<<poolBlocks, 256, 0, stream>>>(p.hB, p.batch, p.P, p.cnt, N, 128);

  fused_gin_k<<<fBlocks, 256, 0, stream>>>(p.hB, p.rowstart, p.eidx,
      p.whi[3], p.wlo[3], p.bias[3], p.whi[4], p.wlo[4], p.bias[4], p.hA, N);
  pool128<false><<<poolBlocks, 256, 0, stream>>>(p.hA, p.batch, p.P, p.cnt, N, 256);

  jk_gemm<<<NGRAPH / 2, 256, 0, stream>>>(p.P, p.cnt, p.jkw, p.jkb, p.gbuf);
  gemm_bn<<<NGRAPH / 64, 256, 0, stream>>>(p.gbuf, p.c1w, p.c1b, p.zc, p.bnstat, NGRAPH);
  bn_final<<<(NGRAPH + 255) / 256, 256, 0, stream>>>(p.zc, p.bnstat, p.bng, p.bnb,
      p.c2w, p.c2b, (float*)d_out);
}

// Round 16
// 460.357 us; speedup vs baseline: 4.0704x; 4.0704x over previous
//
#include <hip/hip_runtime.h>

#define NGRAPH 2048

typedef __attribute__((ext_vector_type(8))) short bf16x8;
typedef __attribute__((ext_vector_type(4))) float f32x4;
typedef __attribute__((ext_vector_type(8))) _Float16 h16x8;
typedef __attribute__((ext_vector_type(4))) _Float16 h16x4;

__device__ inline unsigned short bf16_rne(float f) {
  union { float f; unsigned u; } c; c.f = f;
  unsigned u = c.u + 0x7fffu + ((c.u >> 16) & 1u);
  return (unsigned short)(u >> 16);
}
__device__ inline float bf16_to_f32(unsigned short h) {
  union { float f; unsigned u; } c; c.u = ((unsigned)h) << 16;
  return c.f;
}

// ================= single-pass scan (ticket + decoupled lookback, UNSIGNED flags) =================
// scanst[c]: bits 31:30 = flag (0=empty, 1=aggregate, 2=inclusive prefix), 29:0 = value (E < 2^30)
// scanst[nchunk] = ticket counter. All zeroed before launch.
__global__ __launch_bounds__(256) void scan_onepass(
    const int* __restrict__ deg, int* __restrict__ rowstart,
    unsigned* __restrict__ scanst, int N, int E, int nchunk)
{
  __shared__ int tmp[256];
  __shared__ int sh_chunk;
  __shared__ int sh_exc;
  int tid = threadIdx.x;
  if (tid == 0) sh_chunk = (int)atomicAdd(&scanst[nchunk], 1u);
  __syncthreads();
  int cb = sh_chunk;
  int i = cb * 256 + tid;
  int v = (i < N) ? deg[i] : 0;
  tmp[tid] = v;
  __syncthreads();
#pragma unroll
  for (int off = 1; off < 256; off <<= 1) {
    int t = (tid >= off) ? tmp[tid - off] : 0;
    __syncthreads();
    tmp[tid] += t;
    __syncthreads();
  }
  int aggregate = tmp[255];

  if (tid == 0) {
    const unsigned VMASK = (1u << 30) - 1u;
    if (cb == 0) {
      atomicExch(&scanst[0], (2u << 30) | (unsigned)aggregate);
      sh_exc = 0;
    } else {
      atomicExch(&scanst[cb], (1u << 30) | (unsigned)aggregate);
      int excv = 0;
      int j = cb - 1;
      while (j >= 0) {
        unsigned s;
        do { s = atomicAdd(&scanst[j], 0u); } while ((s >> 30) == 0u);
        excv += (int)(s & VMASK);
        if ((s >> 30) == 2u) break;
        --j;
      }
      sh_exc = excv;
      atomicExch(&scanst[cb], (2u << 30) | (unsigned)(excv + aggregate));
    }
  }
  __syncthreads();
  int exc = sh_exc;
  if (i < N) rowstart[i] = exc + tmp[tid] - v;
  if (cb == nchunk - 1 && tid == 0) rowstart[N] = E;
}

__global__ __launch_bounds__(256) void fill_eidx(
    const int* __restrict__ src, const int* __restrict__ dst,
    const int* __restrict__ rowstart, int* __restrict__ cursor,
    int* __restrict__ eidx, int E)
{
  int e = blockIdx.x * 256 + threadIdx.x;
  if (e >= E) return;
  int d = dst[e];
  int pos = rowstart[d] + atomicAdd(&cursor[d], 1);
  eidx[pos] = src[e];
}

// ====== merged: degree hist + 5x weight frag-repack + x pad + zero(P,cnt,bnstat) ======
struct WPs {
  const float* w[5];
  unsigned short* hi[5];
  unsigned short* lo[5];
};
__global__ __launch_bounds__(256) void prep_hist(
    WPs p, const float* __restrict__ x, float* __restrict__ x8, int N,
    const int* __restrict__ dst, int* __restrict__ deg, int E,
    float4* __restrict__ zeroBase, int zeroCount)
{
  int g = blockIdx.x * 256 + threadIdx.x;
  if (g < E) {
    atomicAdd(&deg[dst[g]], 1);
    return;
  }
  int q = g - E;
  if (q < 5 * 16384) {
    int m = q >> 14;
    int j = q & 16383;
    int c = j >> 3, e = j & 7;
    int t = c >> 8, kc = (c >> 6) & 3, lane = c & 63;
    int n = t * 16 + (lane & 15);
    int k = kc * 32 + (lane >> 4) * 8 + e;
    float w = p.w[m][k * 128 + n];
    unsigned short h = bf16_rne(w);
    p.hi[m][j] = h;
    p.lo[m][j] = bf16_rne(w - bf16_to_f32(h));
    return;
  }
  q -= 5 * 16384;
  if (q < N * 8) {
    int v = q >> 3, j = q & 7;
    x8[q] = (j < 7) ? x[(long)v * 7 + j] : 0.f;
    return;
  }
  q -= N * 8;
  if (q < zeroCount) zeroBase[q] = (float4){0.f, 0.f, 0.f, 0.f};
}

// ---- split-precision GEMM pass over a 64x128 fp16 LDS tile (chunk-rot swizzle) ----
__device__ inline void mfma_pass(
    const _Float16* __restrict__ zbuf,
    const unsigned short* __restrict__ Whi, const unsigned short* __restrict__ Wlo,
    int rw, int m16, int quad, int lane, f32x4 acc[8])
{
  int r = rw + m16;
  const _Float16* zrow = &zbuf[r * 128];
#pragma unroll
  for (int kc = 0; kc < 4; ++kc) {
    int cidx = kc * 4 + quad;
    h16x8 zh = *(const h16x8*)&zrow[((cidx + r) & 15) * 8];
    bf16x8 ah, al;
#pragma unroll
    for (int j = 0; j < 8; ++j) {
      float f = (float)zh[j];
      unsigned short h = bf16_rne(f);
      ah[j] = (short)h;
      al[j] = (short)bf16_rne(f - bf16_to_f32(h));
    }
#pragma unroll
    for (int t = 0; t < 8; ++t) {
      long cb = ((t * 4 + kc) * 64 + lane) * 8;
      bf16x8 bh = *(const bf16x8*)&Whi[cb];
      bf16x8 bl = *(const bf16x8*)&Wlo[cb];
      acc[t] = __builtin_amdgcn_mfma_f32_16x16x32_bf16(ah, bh, acc[t], 0, 0, 0);
      acc[t] = __builtin_amdgcn_mfma_f32_16x16x32_bf16(ah, bl, acc[t], 0, 0, 0);
      acc[t] = __builtin_amdgcn_mfma_f32_16x16x32_bf16(al, bh, acc[t], 0, 0, 0);
    }
  }
}

// ================= fused GIN layer (layers 2,3): gather + MLP1 + MLP2 =================
__global__ __launch_bounds__(256, 8) void fused_gin(
    const _Float16* __restrict__ H, const int* __restrict__ rowstart,
    const int* __restrict__ eidx,
    const unsigned short* __restrict__ W1hi, const unsigned short* __restrict__ W1lo,
    const float* __restrict__ B1,
    const unsigned short* __restrict__ W2hi, const unsigned short* __restrict__ W2lo,
    const float* __restrict__ B2,
    _Float16* __restrict__ Out, int M)
{
  __shared__ _Float16 zbuf[64 * 128];   // 16 KB
  int tid = threadIdx.x;
  int rbase = blockIdx.x * 64;

  {
    int sub = tid & 15;
    int ng = tid >> 4;
    const _Float16* Hc = H + sub * 8;
#pragma unroll
    for (int it = 0; it < 4; ++it) {
      int r = it * 16 + ng;
      int v = rbase + r;
      int vc = (v < M) ? v : (M - 1);
      h16x8 sv = *(const h16x8*)&Hc[(long)vc * 128];
      float a0[8], a1[8];
#pragma unroll
      for (int j = 0; j < 8; ++j) { a0[j] = (float)sv[j]; a1[j] = 0.f; }
      int e0 = rowstart[vc], e1 = rowstart[vc + 1];
      int e = e0;
      for (; e + 4 <= e1; e += 4) {
        int s0 = eidx[e], s1 = eidx[e + 1], s2 = eidx[e + 2], s3 = eidx[e + 3];
        h16x8 h0 = *(const h16x8*)&Hc[(long)s0 * 128];
        h16x8 h1 = *(const h16x8*)&Hc[(long)s1 * 128];
        h16x8 h2 = *(const h16x8*)&Hc[(long)s2 * 128];
        h16x8 h3 = *(const h16x8*)&Hc[(long)s3 * 128];
#pragma unroll
        for (int j = 0; j < 8; ++j) {
          a0[j] += (float)h0[j] + (float)h2[j];
          a1[j] += (float)h1[j] + (float)h3[j];
        }
      }
      for (; e < e1; ++e) {
        int s = eidx[e];
        h16x8 h = *(const h16x8*)&Hc[(long)s * 128];
#pragma unroll
        for (int j = 0; j < 8; ++j) a1[j] += (float)h[j];
      }
      h16x8 zo;
#pragma unroll
      for (int j = 0; j < 8; ++j) zo[j] = (_Float16)(a0[j] + a1[j]);
      *(h16x8*)&zbuf[r * 128 + ((sub + r) & 15) * 8] = zo;
    }
  }
  __syncthreads();

  int lane = tid & 63;
  int wv = tid >> 6;
  int m16 = lane & 15;
  int quad = lane >> 4;
  int rw = wv * 16;

  f32x4 acc[8];
#pragma unroll
  for (int t = 0; t < 8; ++t) acc[t] = (f32x4){0.f, 0.f, 0.f, 0.f};
  mfma_pass(zbuf, W1hi, W1lo, rw, m16, quad, lane, acc);

  float bias[8];
#pragma unroll
  for (int t = 0; t < 8; ++t) bias[t] = B1[t * 16 + m16];

  __syncthreads();
#pragma unroll
  for (int i = 0; i < 4; ++i) {
    int r = rw + quad * 4 + i;
#pragma unroll
    for (int t = 0; t < 8; ++t) {
      int col = t * 16 + m16;
      int cidx = col >> 3;
      zbuf[r * 128 + ((cidx + r) & 15) * 8 + (col & 7)] =
          (_Float16)fmaxf(acc[t][i] + bias[t], 0.f);
    }
  }
  __syncthreads();

#pragma unroll
  for (int t = 0; t < 8; ++t) acc[t] = (f32x4){0.f, 0.f, 0.f, 0.f};
  mfma_pass(zbuf, W2hi, W2lo, rw, m16, quad, lane, acc);

#pragma unroll
  for (int t = 0; t < 8; ++t) bias[t] = B2[t * 16 + m16];

#pragma unroll
  for (int i = 0; i < 4; ++i) {
    int r = rbase + rw + quad * 4 + i;
    if (r < M) {
#pragma unroll
      for (int t = 0; t < 8; ++t) {
        float o = fmaxf(acc[t][i] + bias[t], 0.f);
        Out[(long)r * 128 + t * 16 + m16] = (_Float16)o;
      }
    }
  }
}

// ================= fused layer 1: gather(x8) + K=7 GEMM + MFMA GEMM =================
__global__ __launch_bounds__(256, 8) void fused_l1(
    const float* __restrict__ x8, const int* __restrict__ rowstart,
    const int* __restrict__ eidx,
    const float* __restrict__ W1, const float* __restrict__ B1,
    const unsigned short* __restrict__ W2hi, const unsigned short* __restrict__ W2lo,
    const float* __restrict__ B2, _Float16* __restrict__ Out, int M)
{
  __shared__ _Float16 ybuf[64 * 128];
  __shared__ float z1s[64][8];
  int tid = threadIdx.x;
  int rbase = blockIdx.x * 64;

  {
    int node = tid >> 2, sub = tid & 3;
    int c = (sub & 1) * 4, par = sub >> 1;
    int v = rbase + node;
    int vc = (v < M) ? v : (M - 1);
    const float* Xc = x8 + c;
    float4 a = {0.f, 0.f, 0.f, 0.f};
    float4 a1 = {0.f, 0.f, 0.f, 0.f};
    if (!par) a = *(const float4*)&Xc[(long)vc * 8];
    int e0 = rowstart[vc], e1 = rowstart[vc + 1];
    int e = e0 + par;
    for (; e + 2 < e1; e += 4) {
      int s0 = eidx[e], s1 = eidx[e + 2];
      float4 h0 = *(const float4*)&Xc[(long)s0 * 8];
      float4 h1 = *(const float4*)&Xc[(long)s1 * 8];
      a.x += h0.x; a.y += h0.y; a.z += h0.z; a.w += h0.w;
      a1.x += h1.x; a1.y += h1.y; a1.z += h1.z; a1.w += h1.w;
    }
    for (; e < e1; e += 2) {
      int s = eidx[e];
      float4 h = *(const float4*)&Xc[(long)s * 8];
      a.x += h.x; a.y += h.y; a.z += h.z; a.w += h.w;
    }
    a.x += a1.x; a.y += a1.y; a.z += a1.z; a.w += a1.w;
    if (par) *(float4*)&z1s[node][c] = a;
    __syncthreads();
    if (!par) {
      float4 b = *(const float4*)&z1s[node][c];
      a.x += b.x; a.y += b.y; a.z += b.z; a.w += b.w;
      *(float4*)&z1s[node][c] = a;
    }
  }
  __syncthreads();

  {
    int c = tid & 127;
    int cidx = c >> 3, celt = c & 7;
    int rh0 = (tid >> 7) * 32;
    float w1r[7];
#pragma unroll
    for (int k = 0; k < 7; ++k) w1r[k] = W1[k * 128 + c];
    float b1 = B1[c];
#pragma unroll 4
    for (int rr = 0; rr < 32; ++rr) {
      int r = rh0 + rr;
      const float* zp = z1s[r];
      float a = b1;
#pragma unroll
      for (int k = 0; k < 7; ++k) a += zp[k] * w1r[k];
      ybuf[r * 128 + ((cidx + r) & 15) * 8 + celt] = (_Float16)fmaxf(a, 0.f);
    }
  }
  __syncthreads();

  int lane = tid & 63;
  int wv = tid >> 6;
  int m16 = lane & 15;
  int quad = lane >> 4;
  int rw = wv * 16;

  f32x4 acc[8];
#pragma unroll
  for (int t = 0; t < 8; ++t) acc[t] = (f32x4){0.f, 0.f, 0.f, 0.f};
  mfma_pass(ybuf, W2hi, W2lo, rw, m16, quad, lane, acc);

  float bias[8];
#pragma unroll
  for (int t = 0; t < 8; ++t) bias[t] = B2[t * 16 + m16];

#pragma unroll
  for (int i = 0; i < 4; ++i) {
    int r = rbase + rw + quad * 4 + i;
    if (r < M) {
#pragma unroll
      for (int t = 0; t < 8; ++t) {
        float o = fmaxf(acc[t][i] + bias[t], 0.f);
        Out[(long)r * 128 + t * 16 + m16] = (_Float16)o;
      }
    }
  }
}

// ================= pooling, all 3 layers in one pass =================
__global__ __launch_bounds__(256) void pool_all(
    const _Float16* __restrict__ H1, const _Float16* __restrict__ H2,
    const _Float16* __restrict__ H3, const int* __restrict__ batch,
    float* __restrict__ P, float* __restrict__ cnt, int Nn)
{
  long t = (long)blockIdx.x * 256 + threadIdx.x;
  int cg = (int)(t & 31);
  int chunk = (int)(t >> 5);
  int i0 = chunk * 16;
  if (i0 >= Nn) return;
  int c = cg * 4;
  float4 a1 = {0.f,0.f,0.f,0.f}, a2 = {0.f,0.f,0.f,0.f}, a3 = {0.f,0.f,0.f,0.f};
  int curb = -1;
  float runc = 0.f;
  for (int ii = 0; ii < 16; ++ii) {
    int i = i0 + ii;
    if (i >= Nn) break;
    int b = batch[i];
    if (b != curb) {
      if (curb >= 0) {
        float* p = &P[(long)curb * 384 + c];
        atomicAdd(p + 0, a1.x); atomicAdd(p + 1, a1.y);
        atomicAdd(p + 2, a1.z); atomicAdd(p + 3, a1.w);
        atomicAdd(p + 128, a2.x); atomicAdd(p + 129, a2.y);
        atomicAdd(p + 130, a2.z); atomicAdd(p + 131, a2.w);
        atomicAdd(p + 256, a3.x); atomicAdd(p + 257, a3.y);
        atomicAdd(p + 258, a3.z); atomicAdd(p + 259, a3.w);
        if (cg == 0) atomicAdd(&cnt[curb], runc);
      }
      a1 = (float4){0.f,0.f,0.f,0.f};
      a2 = (float4){0.f,0.f,0.f,0.f};
      a3 = (float4){0.f,0.f,0.f,0.f};
      runc = 0.f;
      curb = b;
    }
    h16x4 v1 = *(const h16x4*)&H1[(long)i * 128 + c];
    h16x4 v2 = *(const h16x4*)&H2[(long)i * 128 + c];
    h16x4 v3 = *(const h16x4*)&H3[(long)i * 128 + c];
    a1.x += (float)v1[0]; a1.y += (float)v1[1]; a1.z += (float)v1[2]; a1.w += (float)v1[3];
    a2.x += (float)v2[0]; a2.y += (float)v2[1]; a2.z += (float)v2[2]; a2.w += (float)v2[3];
    a3.x += (float)v3[0]; a3.y += (float)v3[1]; a3.z += (float)v3[2]; a3.w += (float)v3[3];
    runc += 1.f;
  }
  if (curb >= 0) {
    float* p = &P[(long)curb * 384 + c];
    atomicAdd(p + 0, a1.x); atomicAdd(p + 1, a1.y);
    atomicAdd(p + 2, a1.z); atomicAdd(p + 3, a1.w);
    atomicAdd(p + 128, a2.x); atomicAdd(p + 129, a2.y);
    atomicAdd(p + 130, a2.z); atomicAdd(p + 131, a2.w);
    atomicAdd(p + 256, a3.x); atomicAdd(p + 257, a3.y);
    atomicAdd(p + 258, a3.z); atomicAdd(p + 259, a3.w);
    if (cg == 0) atomicAdd(&cnt[curb], runc);
  }
}

// ================= JK: G = P(2048x384) @ W(384x128) + cnt*B  (1024 blocks) =================
__global__ __launch_bounds__(256) void jk_gemm(
    const float* __restrict__ P, const float* __restrict__ cnt,
    const float* __restrict__ W, const float* __restrict__ B,
    float* __restrict__ G)
{
  __shared__ float pl[768];
  int tid = threadIdx.x, blk = blockIdx.x;
  for (int o = tid; o < 768; o += 256) pl[o] = P[(long)blk * 768 + o];
  __syncthreads();
  int rr = tid >> 7;
  int col = tid & 127;
  int row = blk * 2 + rr;
  float acc = cnt[row] * B[col];
#pragma unroll 8
  for (int k = 0; k < 384; ++k)
    acc += pl[rr * 384 + k] * W[k * 128 + col];
  G[(long)row * 128 + col] = acc;
}

// ================= classifier GEMM + BN stat atomics =================
__global__ __launch_bounds__(256) void gemm_bn(
    const float* __restrict__ Z,
    const float* __restrict__ W, const float* __restrict__ B,
    float* __restrict__ Out, float* __restrict__ bnstat, int M)
{
  __shared__ float wlds[128 * 128];
  int tid = threadIdx.x;
  {
    const float4* Ws = (const float4*)W;
    float4* Wd = (float4*)wlds;
#pragma unroll
    for (int i = 0; i < 16; ++i) Wd[i * 256 + tid] = Ws[i * 256 + tid];
  }
  __syncthreads();

  int rg = tid >> 5;
  int c0 = (tid & 31) * 4;
  int rbase = blockIdx.x * 64 + rg * 8;

  float acc[8][4];
#pragma unroll
  for (int i = 0; i < 8; ++i)
#pragma unroll
    for (int j = 0; j < 4; ++j) acc[i][j] = 0.f;

#pragma unroll 2
  for (int kc = 0; kc < 128; kc += 4) {
    float zv[8][4];
#pragma unroll
    for (int i = 0; i < 8; ++i) {
      float4 z = *(const float4*)&Z[(long)(rbase + i) * 128 + kc];
      zv[i][0] = z.x; zv[i][1] = z.y; zv[i][2] = z.z; zv[i][3] = z.w;
    }
#pragma unroll
    for (int kk = 0; kk < 4; ++kk) {
      float4 w = *(const float4*)&wlds[(kc + kk) * 128 + c0];
#pragma unroll
      for (int i = 0; i < 8; ++i) {
        float z = zv[i][kk];
        acc[i][0] += z * w.x; acc[i][1] += z * w.y;
        acc[i][2] += z * w.z; acc[i][3] += z * w.w;
      }
    }
  }

  float4 b = *(const float4*)&B[c0];
  float s[4] = {0.f, 0.f, 0.f, 0.f};
  float s2[4] = {0.f, 0.f, 0.f, 0.f};
#pragma unroll
  for (int i = 0; i < 8; ++i) {
    float4 o;
    o.x = acc[i][0] + b.x; o.y = acc[i][1] + b.y;
    o.z = acc[i][2] + b.z; o.w = acc[i][3] + b.w;
    *(float4*)&Out[(long)(rbase + i) * 128 + c0] = o;
    s[0] += o.x; s[1] += o.y; s[2] += o.z; s[3] += o.w;
    s2[0] += o.x * o.x; s2[1] += o.y * o.y; s2[2] += o.z * o.z; s2[3] += o.w * o.w;
  }
#pragma unroll
  for (int j = 0; j < 4; ++j) {
    atomicAdd(&bnstat[c0 + j], s[j]);
    atomicAdd(&bnstat[128 + c0 + j], s2[j]);
  }
}

// ================= BN apply + relu + final [128x2] matmul =================
__global__ __launch_bounds__(256) void bn_final(
    const float* __restrict__ ZC, const float* __restrict__ bnstat,
    const float* __restrict__ gma, const float* __restrict__ bta,
    const float* __restrict__ W2, const float* __restrict__ B2, float* __restrict__ out)
{
  __shared__ float scl[128], shf[128];
  int tid = threadIdx.x;
  if (tid < 128) {
    float mu = bnstat[tid] * (1.f / NGRAPH);
    float var = bnstat[128 + tid] * (1.f / NGRAPH) - mu * mu;
    float rs = rsqrtf(var + 1e-5f);
    float sc = gma[tid] * rs;
    scl[tid] = sc;
    shf[tid] = bta[tid] - mu * sc;
  }
  __syncthreads();
  int g = blockIdx.x * 256 + tid;
  if (g >= NGRAPH) return;
  float a0 = B2[0], a1 = B2[1];
#pragma unroll 4
  for (int h = 0; h < 128; ++h) {
    float zn = ZC[(long)g * 128 + h] * scl[h] + shf[h];
    zn = fmaxf(zn, 0.f);
    a0 += zn * W2[2 * h];
    a1 += zn * W2[2 * h + 1];
  }
  out[2 * g] = a0;
  out[2 * g + 1] = a1;
}

extern "C" void kernel_launch(void* const* d_in, const int* in_sizes, int n_in,
                              void* d_out, int out_size, void* d_ws, size_t ws_size,
                              hipStream_t stream)
{
  const float* x    = (const float*)d_in[0];
  const int*   ei   = (const int*)d_in[1];
  const int*   batch = (const int*)d_in[3];
  const float* g1w1 = (const float*)d_in[4];  const float* g1b1 = (const float*)d_in[5];
  const float* g1w2 = (const float*)d_in[6];  const float* g1b2 = (const float*)d_in[7];
  const float* g2w1 = (const float*)d_in[8];  const float* g2b1 = (const float*)d_in[9];
  const float* g2w2 = (const float*)d_in[10]; const float* g2b2 = (const float*)d_in[11];
  const float* g3w1 = (const float*)d_in[12]; const float* g3b1 = (const float*)d_in[13];
  const float* g3w2 = (const float*)d_in[14]; const float* g3b2 = (const float*)d_in[15];
  const float* jkw  = (const float*)d_in[16]; const float* jkb  = (const float*)d_in[17];
  const float* c1w  = (const float*)d_in[18]; const float* c1b  = (const float*)d_in[19];
  const float* bng  = (const float*)d_in[20]; const float* bnb  = (const float*)d_in[21];
  const float* c2w  = (const float*)d_in[22]; const float* c2b  = (const float*)d_in[23];

  const int N = in_sizes[3];
  const int E = in_sizes[1] / 2;
  const int* src = ei;
  const int* dst = ei + E;

  char* w = (char*)d_ws;
  auto alloc = [&](size_t bytes) {
    char* p = w;
    w += (bytes + 255) & ~(size_t)255;
    return p;
  };
  _Float16* hA = (_Float16*)alloc((size_t)N * 128 * 2);   // layer-3 out
  _Float16* hB = (_Float16*)alloc((size_t)N * 128 * 2);   // layer-2 out
  _Float16* hC = (_Float16*)alloc((size_t)N * 128 * 2);   // layer-1 out
  float* x8   = (float*)alloc((size_t)N * 8 * 4);
  // P, cnt, bnstat contiguous -> zeroed by prep_hist
  float* P       = (float*)alloc((size_t)NGRAPH * 384 * 4);
  float* cnt     = (float*)alloc((size_t)NGRAPH * 4);
  float* bnstat  = (float*)alloc(256 * 4);
  float* gbuf = (float*)alloc((size_t)NGRAPH * 128 * 4);
  float* zc   = (float*)alloc((size_t)NGRAPH * 128 * 4);
  // deg, cursor, scanst contiguous -> one memset
  int* deg      = (int*)alloc((size_t)N * 4);
  int* cursor   = (int*)alloc((size_t)N * 4);
  unsigned* scanst = (unsigned*)alloc((size_t)1024 * 4);
  int* rowstart = (int*)alloc((size_t)(N + 1) * 4);
  int* eidx     = (int*)alloc((size_t)E * 4);
  unsigned short* wtbuf = (unsigned short*)alloc((size_t)5 * 2 * 16384 * 2);

  unsigned short* WThi[5];
  unsigned short* WTlo[5];
  for (int m = 0; m < 5; ++m) {
    WThi[m] = wtbuf + (size_t)m * 2 * 16384;
    WTlo[m] = WThi[m] + 16384;
  }

  const int nchunk = (N + 255) / 256;
  const int eb = (E + 255) / 256;

  // ---- memset deg+cursor+scanst (contiguous allocs incl. padding) ----
  hipMemsetAsync(deg, 0, (size_t)((char*)(scanst + 1024) - (char*)deg), stream);

  // ---- merged hist + weight prep + x pad + zero(P,cnt,bnstat) ----
  {
    WPs p;
    p.w[0] = g1w2; p.w[1] = g2w1; p.w[2] = g2w2; p.w[3] = g3w1; p.w[4] = g3w2;
    for (int m = 0; m < 5; ++m) { p.hi[m] = WThi[m]; p.lo[m] = WTlo[m]; }
    int zeroCount = (NGRAPH * 384 + NGRAPH + 256) / 4;   // float4 count over P..bnstat
    int total = E + 5 * 16384 + N * 8 + zeroCount;
    prep_hist<<<(total + 255) / 256, 256, 0, stream>>>(p, x, x8, N, dst, deg, E,
                                                       (float4*)P, zeroCount);
  }

  // ---- single-pass scan + fill ----
  scan_onepass<<<nchunk, 256, 0, stream>>>(deg, rowstart, scanst, N, E, nchunk);
  fill_eidx<<<eb, 256, 0, stream>>>(src, dst, rowstart, cursor, eidx, E);

  const int fBlocks = (N + 63) / 64;
  const int poolBlocks = (((N + 15) / 16) * 32 + 255) / 256;

  // ---- layers ----
  fused_l1<<<fBlocks, 256, 0, stream>>>(x8, rowstart, eidx, g1w1, g1b1,
      WThi[0], WTlo[0], g1b2, hC, N);
  fused_gin<<<fBlocks, 256, 0, stream>>>(hC, rowstart, eidx,
      WThi[1], WTlo[1], g2b1, WThi[2], WTlo[2], g2b2, hB, N);
  fused_gin<<<fBlocks, 256, 0, stream>>>(hB, rowstart, eidx,
      WThi[3], WTlo[3], g3b1, WThi[4], WTlo[4], g3b2, hA, N);

  // ---- pooling (all 3 layers, one pass) ----
  pool_all<<<poolBlocks, 256, 0, stream>>>(hC, hB, hA, batch, P, cnt, N);

  // ---- head ----
  jk_gemm<<<NGRAPH / 2, 256, 0, stream>>>(P, cnt, jkw, jkb, gbuf);
  gemm_bn<<<NGRAPH / 64, 256, 0, stream>>>(gbuf, c1w, c1b, zc, bnstat, NGRAPH);
  bn_final<<<(NGRAPH + 255) / 256, 256, 0, stream>>>(zc, bnstat, bng, bnb, c2w, c2b, (float*)d_out);
}

// Round 17
// 447.673 us; speedup vs baseline: 4.1857x; 1.0283x over previous
//
#include <hip/hip_runtime.h>

#define NGRAPH 2048

typedef __attribute__((ext_vector_type(8))) short bf16x8;
typedef __attribute__((ext_vector_type(4))) float f32x4;
typedef __attribute__((ext_vector_type(8))) _Float16 h16x8;
typedef __attribute__((ext_vector_type(4))) _Float16 h16x4;

__device__ inline unsigned short bf16_rne(float f) {
  union { float f; unsigned u; } c; c.f = f;
  unsigned u = c.u + 0x7fffu + ((c.u >> 16) & 1u);
  return (unsigned short)(u >> 16);
}
__device__ inline float bf16_to_f32(unsigned short h) {
  union { float f; unsigned u; } c; c.u = ((unsigned)h) << 16;
  return c.f;
}

// ================= single-pass scan (ticket + decoupled lookback, unsigned flags) =================
// also initializes cursor[i] = rowstart[i] so fill_eidx needs no rowstart read
__global__ __launch_bounds__(256) void scan_onepass(
    const int* __restrict__ deg, int* __restrict__ rowstart, int* __restrict__ cursor,
    unsigned* __restrict__ scanst, int N, int E, int nchunk)
{
  __shared__ int tmp[256];
  __shared__ int sh_chunk;
  __shared__ int sh_exc;
  int tid = threadIdx.x;
  if (tid == 0) sh_chunk = (int)atomicAdd(&scanst[nchunk], 1u);
  __syncthreads();
  int cb = sh_chunk;
  int i = cb * 256 + tid;
  int v = (i < N) ? deg[i] : 0;
  tmp[tid] = v;
  __syncthreads();
#pragma unroll
  for (int off = 1; off < 256; off <<= 1) {
    int t = (tid >= off) ? tmp[tid - off] : 0;
    __syncthreads();
    tmp[tid] += t;
    __syncthreads();
  }
  int aggregate = tmp[255];

  if (tid == 0) {
    const unsigned VMASK = (1u << 30) - 1u;
    if (cb == 0) {
      atomicExch(&scanst[0], (2u << 30) | (unsigned)aggregate);
      sh_exc = 0;
    } else {
      atomicExch(&scanst[cb], (1u << 30) | (unsigned)aggregate);
      int excv = 0;
      int j = cb - 1;
      while (j >= 0) {
        unsigned s;
        do { s = atomicAdd(&scanst[j], 0u); } while ((s >> 30) == 0u);
        excv += (int)(s & VMASK);
        if ((s >> 30) == 2u) break;
        --j;
      }
      sh_exc = excv;
      atomicExch(&scanst[cb], (2u << 30) | (unsigned)(excv + aggregate));
    }
  }
  __syncthreads();
  int exc = sh_exc;
  if (i < N) {
    int rs = exc + tmp[tid] - v;
    rowstart[i] = rs;
    cursor[i] = rs;
  }
  if (cb == nchunk - 1 && tid == 0) rowstart[N] = E;
}

__global__ __launch_bounds__(256) void fill_eidx(
    const int* __restrict__ src, const int* __restrict__ dst,
    int* __restrict__ cursor, int* __restrict__ eidx, int E)
{
  int e = blockIdx.x * 256 + threadIdx.x;
  if (e >= E) return;
  int d = dst[e];
  int pos = atomicAdd(&cursor[d], 1);
  eidx[pos] = src[e];
}

// ====== merged: degree hist + 5x weight frag-repack + x pad(fp16) + zero(P,cnt,bnstat) ======
struct WPs {
  const float* w[5];
  unsigned short* hi[5];
  unsigned short* lo[5];
};
__global__ __launch_bounds__(256) void prep_hist(
    WPs p, const float* __restrict__ x, _Float16* __restrict__ x8h, int N,
    const int* __restrict__ dst, int* __restrict__ deg, int E,
    float4* __restrict__ zeroBase, int zeroCount)
{
  int g = blockIdx.x * 256 + threadIdx.x;
  if (g < E) {
    atomicAdd(&deg[dst[g]], 1);
    return;
  }
  int q = g - E;
  if (q < 5 * 16384) {
    int m = q >> 14;
    int j = q & 16383;
    int c = j >> 3, e = j & 7;
    int t = c >> 8, kc = (c >> 6) & 3, lane = c & 63;
    int n = t * 16 + (lane & 15);
    int k = kc * 32 + (lane >> 4) * 8 + e;
    float w = p.w[m][k * 128 + n];
    unsigned short h = bf16_rne(w);
    p.hi[m][j] = h;
    p.lo[m][j] = bf16_rne(w - bf16_to_f32(h));
    return;
  }
  q -= 5 * 16384;
  if (q < N * 8) {
    int v = q >> 3, j = q & 7;
    x8h[q] = (_Float16)((j < 7) ? x[(long)v * 7 + j] : 0.f);
    return;
  }
  q -= N * 8;
  if (q < zeroCount) zeroBase[q] = (float4){0.f, 0.f, 0.f, 0.f};
}

// ---- split-precision GEMM pass over a 64x128 fp16 LDS tile (chunk-rot swizzle) ----
__device__ inline void mfma_pass(
    const _Float16* __restrict__ zbuf,
    const unsigned short* __restrict__ Whi, const unsigned short* __restrict__ Wlo,
    int rw, int m16, int quad, int lane, f32x4 acc[8])
{
  int r = rw + m16;
  const _Float16* zrow = &zbuf[r * 128];
#pragma unroll
  for (int kc = 0; kc < 4; ++kc) {
    int cidx = kc * 4 + quad;
    h16x8 zh = *(const h16x8*)&zrow[((cidx + r) & 15) * 8];
    bf16x8 ah, al;
#pragma unroll
    for (int j = 0; j < 8; ++j) {
      float f = (float)zh[j];
      unsigned short h = bf16_rne(f);
      ah[j] = (short)h;
      al[j] = (short)bf16_rne(f - bf16_to_f32(h));
    }
#pragma unroll
    for (int t = 0; t < 8; ++t) {
      long cb = ((t * 4 + kc) * 64 + lane) * 8;
      bf16x8 bh = *(const bf16x8*)&Whi[cb];
      bf16x8 bl = *(const bf16x8*)&Wlo[cb];
      acc[t] = __builtin_amdgcn_mfma_f32_16x16x32_bf16(ah, bh, acc[t], 0, 0, 0);
      acc[t] = __builtin_amdgcn_mfma_f32_16x16x32_bf16(ah, bl, acc[t], 0, 0, 0);
      acc[t] = __builtin_amdgcn_mfma_f32_16x16x32_bf16(al, bh, acc[t], 0, 0, 0);
    }
  }
}

// ================= fused GIN layer (layers 2,3): gather + MLP1 + MLP2 =================
__global__ __launch_bounds__(256, 8) void fused_gin(
    const _Float16* __restrict__ H, const int* __restrict__ rowstart,
    const int* __restrict__ eidx,
    const unsigned short* __restrict__ W1hi, const unsigned short* __restrict__ W1lo,
    const float* __restrict__ B1,
    const unsigned short* __restrict__ W2hi, const unsigned short* __restrict__ W2lo,
    const float* __restrict__ B2,
    _Float16* __restrict__ Out, int M)
{
  __shared__ _Float16 zbuf[64 * 128];   // 16 KB
  int tid = threadIdx.x;
  int rbase = blockIdx.x * 64;

  {
    int sub = tid & 15;
    int ng = tid >> 4;
    const _Float16* Hc = H + sub * 8;
#pragma unroll
    for (int it = 0; it < 4; ++it) {
      int r = it * 16 + ng;
      int v = rbase + r;
      int vc = (v < M) ? v : (M - 1);
      h16x8 sv = *(const h16x8*)&Hc[(long)vc * 128];
      float a0[8], a1[8];
#pragma unroll
      for (int j = 0; j < 8; ++j) { a0[j] = (float)sv[j]; a1[j] = 0.f; }
      int e0 = rowstart[vc], e1 = rowstart[vc + 1];
      int e = e0;
      for (; e + 4 <= e1; e += 4) {
        int s0 = eidx[e], s1 = eidx[e + 1], s2 = eidx[e + 2], s3 = eidx[e + 3];
        h16x8 h0 = *(const h16x8*)&Hc[(long)s0 * 128];
        h16x8 h1 = *(const h16x8*)&Hc[(long)s1 * 128];
        h16x8 h2 = *(const h16x8*)&Hc[(long)s2 * 128];
        h16x8 h3 = *(const h16x8*)&Hc[(long)s3 * 128];
#pragma unroll
        for (int j = 0; j < 8; ++j) {
          a0[j] += (float)h0[j] + (float)h2[j];
          a1[j] += (float)h1[j] + (float)h3[j];
        }
      }
      for (; e + 2 <= e1; e += 2) {
        int s0 = eidx[e], s1 = eidx[e + 1];
        h16x8 h0 = *(const h16x8*)&Hc[(long)s0 * 128];
        h16x8 h1 = *(const h16x8*)&Hc[(long)s1 * 128];
#pragma unroll
        for (int j = 0; j < 8; ++j) {
          a0[j] += (float)h0[j];
          a1[j] += (float)h1[j];
        }
      }
      if (e < e1) {
        int s = eidx[e];
        h16x8 h = *(const h16x8*)&Hc[(long)s * 128];
#pragma unroll
        for (int j = 0; j < 8; ++j) a1[j] += (float)h[j];
      }
      h16x8 zo;
#pragma unroll
      for (int j = 0; j < 8; ++j) zo[j] = (_Float16)(a0[j] + a1[j]);
      *(h16x8*)&zbuf[r * 128 + ((sub + r) & 15) * 8] = zo;
    }
  }
  __syncthreads();

  int lane = tid & 63;
  int wv = tid >> 6;
  int m16 = lane & 15;
  int quad = lane >> 4;
  int rw = wv * 16;

  f32x4 acc[8];
#pragma unroll
  for (int t = 0; t < 8; ++t) acc[t] = (f32x4){0.f, 0.f, 0.f, 0.f};
  mfma_pass(zbuf, W1hi, W1lo, rw, m16, quad, lane, acc);

  float bias[8];
#pragma unroll
  for (int t = 0; t < 8; ++t) bias[t] = B1[t * 16 + m16];

  __syncthreads();
#pragma unroll
  for (int i = 0; i < 4; ++i) {
    int r = rw + quad * 4 + i;
#pragma unroll
    for (int t = 0; t < 8; ++t) {
      int col = t * 16 + m16;
      int cidx = col >> 3;
      zbuf[r * 128 + ((cidx + r) & 15) * 8 + (col & 7)] =
          (_Float16)fmaxf(acc[t][i] + bias[t], 0.f);
    }
  }
  __syncthreads();

#pragma unroll
  for (int t = 0; t < 8; ++t) acc[t] = (f32x4){0.f, 0.f, 0.f, 0.f};
  mfma_pass(zbuf, W2hi, W2lo, rw, m16, quad, lane, acc);

#pragma unroll
  for (int t = 0; t < 8; ++t) bias[t] = B2[t * 16 + m16];

#pragma unroll
  for (int i = 0; i < 4; ++i) {
    int r = rbase + rw + quad * 4 + i;
    if (r < M) {
#pragma unroll
      for (int t = 0; t < 8; ++t) {
        float o = fmaxf(acc[t][i] + bias[t], 0.f);
        Out[(long)r * 128 + t * 16 + m16] = (_Float16)o;
      }
    }
  }
}

// ================= fused layer 1: gather(x8h fp16) + K=7 GEMM + MFMA GEMM =================
// gather: 4 lanes/node, each lane loads full 16B rows over its edge-parity subset (2-unrolled),
// partials reduced across the quad via shfl_xor.
__global__ __launch_bounds__(256, 8) void fused_l1(
    const _Float16* __restrict__ x8h, const int* __restrict__ rowstart,
    const int* __restrict__ eidx,
    const float* __restrict__ W1, const float* __restrict__ B1,
    const unsigned short* __restrict__ W2hi, const unsigned short* __restrict__ W2lo,
    const float* __restrict__ B2, _Float16* __restrict__ Out, int M)
{
  __shared__ _Float16 ybuf[64 * 128];
  __shared__ float z1s[64][8];
  int tid = threadIdx.x;
  int rbase = blockIdx.x * 64;

  {
    int node = tid >> 2, sub = tid & 3;
    int v = rbase + node;
    int vc = (v < M) ? v : (M - 1);
    float a[8];
    if (sub == 0) {
      h16x8 sv = *(const h16x8*)&x8h[(long)vc * 8];
#pragma unroll
      for (int j = 0; j < 8; ++j) a[j] = (float)sv[j];
    } else {
#pragma unroll
      for (int j = 0; j < 8; ++j) a[j] = 0.f;
    }
    int e0 = rowstart[vc], e1 = rowstart[vc + 1];
    int e = e0 + sub;
    for (; e + 4 < e1; e += 8) {
      int s0 = eidx[e], s1 = eidx[e + 4];
      h16x8 h0 = *(const h16x8*)&x8h[(long)s0 * 8];
      h16x8 h1 = *(const h16x8*)&x8h[(long)s1 * 8];
#pragma unroll
      for (int j = 0; j < 8; ++j) a[j] += (float)h0[j] + (float)h1[j];
    }
    if (e < e1) {
      int s = eidx[e];
      h16x8 h = *(const h16x8*)&x8h[(long)s * 8];
#pragma unroll
      for (int j = 0; j < 8; ++j) a[j] += (float)h[j];
    }
    // reduce across the 4 lanes of the quad
#pragma unroll
    for (int j = 0; j < 8; ++j) {
      a[j] += __shfl_xor(a[j], 1, 64);
      a[j] += __shfl_xor(a[j], 2, 64);
    }
    if (sub == 0) {
#pragma unroll
      for (int j = 0; j < 8; ++j) z1s[node][j] = a[j];
    }
  }
  __syncthreads();

  {
    int c = tid & 127;
    int cidx = c >> 3, celt = c & 7;
    int rh0 = (tid >> 7) * 32;
    float w1r[7];
#pragma unroll
    for (int k = 0; k < 7; ++k) w1r[k] = W1[k * 128 + c];
    float b1 = B1[c];
#pragma unroll 4
    for (int rr = 0; rr < 32; ++rr) {
      int r = rh0 + rr;
      const float* zp = z1s[r];
      float a = b1;
#pragma unroll
      for (int k = 0; k < 7; ++k) a += zp[k] * w1r[k];
      ybuf[r * 128 + ((cidx + r) & 15) * 8 + celt] = (_Float16)fmaxf(a, 0.f);
    }
  }
  __syncthreads();

  int lane = tid & 63;
  int wv = tid >> 6;
  int m16 = lane & 15;
  int quad = lane >> 4;
  int rw = wv * 16;

  f32x4 acc[8];
#pragma unroll
  for (int t = 0; t < 8; ++t) acc[t] = (f32x4){0.f, 0.f, 0.f, 0.f};
  mfma_pass(ybuf, W2hi, W2lo, rw, m16, quad, lane, acc);

  float bias[8];
#pragma unroll
  for (int t = 0; t < 8; ++t) bias[t] = B2[t * 16 + m16];

#pragma unroll
  for (int i = 0; i < 4; ++i) {
    int r = rbase + rw + quad * 4 + i;
    if (r < M) {
#pragma unroll
      for (int t = 0; t < 8; ++t) {
        float o = fmaxf(acc[t][i] + bias[t], 0.f);
        Out[(long)r * 128 + t * 16 + m16] = (_Float16)o;
      }
    }
  }
}

// ================= pooling, all 3 layers in one pass =================
__global__ __launch_bounds__(256) void pool_all(
    const _Float16* __restrict__ H1, const _Float16* __restrict__ H2,
    const _Float16* __restrict__ H3, const int* __restrict__ batch,
    float* __restrict__ P, float* __restrict__ cnt, int Nn)
{
  long t = (long)blockIdx.x * 256 + threadIdx.x;
  int cg = (int)(t & 31);
  int chunk = (int)(t >> 5);
  int i0 = chunk * 16;
  if (i0 >= Nn) return;
  int c = cg * 4;
  float4 a1 = {0.f,0.f,0.f,0.f}, a2 = {0.f,0.f,0.f,0.f}, a3 = {0.f,0.f,0.f,0.f};
  int curb = -1;
  float runc = 0.f;
  for (int ii = 0; ii < 16; ++ii) {
    int i = i0 + ii;
    if (i >= Nn) break;
    int b = batch[i];
    if (b != curb) {
      if (curb >= 0) {
        float* p = &P[(long)curb * 384 + c];
        atomicAdd(p + 0, a1.x); atomicAdd(p + 1, a1.y);
        atomicAdd(p + 2, a1.z); atomicAdd(p + 3, a1.w);
        atomicAdd(p + 128, a2.x); atomicAdd(p + 129, a2.y);
        atomicAdd(p + 130, a2.z); atomicAdd(p + 131, a2.w);
        atomicAdd(p + 256, a3.x); atomicAdd(p + 257, a3.y);
        atomicAdd(p + 258, a3.z); atomicAdd(p + 259, a3.w);
        if (cg == 0) atomicAdd(&cnt[curb], runc);
      }
      a1 = (float4){0.f,0.f,0.f,0.f};
      a2 = (float4){0.f,0.f,0.f,0.f};
      a3 = (float4){0.f,0.f,0.f,0.f};
      runc = 0.f;
      curb = b;
    }
    h16x4 v1 = *(const h16x4*)&H1[(long)i * 128 + c];
    h16x4 v2 = *(const h16x4*)&H2[(long)i * 128 + c];
    h16x4 v3 = *(const h16x4*)&H3[(long)i * 128 + c];
    a1.x += (float)v1[0]; a1.y += (float)v1[1]; a1.z += (float)v1[2]; a1.w += (float)v1[3];
    a2.x += (float)v2[0]; a2.y += (float)v2[1]; a2.z += (float)v2[2]; a2.w += (float)v2[3];
    a3.x += (float)v3[0]; a3.y += (float)v3[1]; a3.z += (float)v3[2]; a3.w += (float)v3[3];
    runc += 1.f;
  }
  if (curb >= 0) {
    float* p = &P[(long)curb * 384 + c];
    atomicAdd(p + 0, a1.x); atomicAdd(p + 1, a1.y);
    atomicAdd(p + 2, a1.z); atomicAdd(p + 3, a1.w);
    atomicAdd(p + 128, a2.x); atomicAdd(p + 129, a2.y);
    atomicAdd(p + 130, a2.z); atomicAdd(p + 131, a2.w);
    atomicAdd(p + 256, a3.x); atomicAdd(p + 257, a3.y);
    atomicAdd(p + 258, a3.z); atomicAdd(p + 259, a3.w);
    if (cg == 0) atomicAdd(&cnt[curb], runc);
  }
}

// ================= JK: G = P(2048x384) @ W(384x128) + cnt*B  (1024 blocks) =================
__global__ __launch_bounds__(256) void jk_gemm(
    const float* __restrict__ P, const float* __restrict__ cnt,
    const float* __restrict__ W, const float* __restrict__ B,
    float* __restrict__ G)
{
  __shared__ float pl[768];
  int tid = threadIdx.x, blk = blockIdx.x;
  for (int o = tid; o < 768; o += 256) pl[o] = P[(long)blk * 768 + o];
  __syncthreads();
  int rr = tid >> 7;
  int col = tid & 127;
  int row = blk * 2 + rr;
  float acc = cnt[row] * B[col];
#pragma unroll 8
  for (int k = 0; k < 384; ++k)
    acc += pl[rr * 384 + k] * W[k * 128 + col];
  G[(long)row * 128 + col] = acc;
}

// ================= classifier GEMM + BN stat atomics =================
__global__ __launch_bounds__(256) void gemm_bn(
    const float* __restrict__ Z,
    const float* __restrict__ W, const float* __restrict__ B,
    float* __restrict__ Out, float* __restrict__ bnstat, int M)
{
  __shared__ float wlds[128 * 128];
  int tid = threadIdx.x;
  {
    const float4* Ws = (const float4*)W;
    float4* Wd = (float4*)wlds;
#pragma unroll
    for (int i = 0; i < 16; ++i) Wd[i * 256 + tid] = Ws[i * 256 + tid];
  }
  __syncthreads();

  int rg = tid >> 5;
  int c0 = (tid & 31) * 4;
  int rbase = blockIdx.x * 64 + rg * 8;

  float acc[8][4];
#pragma unroll
  for (int i = 0; i < 8; ++i)
#pragma unroll
    for (int j = 0; j < 4; ++j) acc[i][j] = 0.f;

#pragma unroll 2
  for (int kc = 0; kc < 128; kc += 4) {
    float zv[8][4];
#pragma unroll
    for (int i = 0; i < 8; ++i) {
      float4 z = *(const float4*)&Z[(long)(rbase + i) * 128 + kc];
      zv[i][0] = z.x; zv[i][1] = z.y; zv[i][2] = z.z; zv[i][3] = z.w;
    }
#pragma unroll
    for (int kk = 0; kk < 4; ++kk) {
      float4 w = *(const float4*)&wlds[(kc + kk) * 128 + c0];
#pragma unroll
      for (int i = 0; i < 8; ++i) {
        float z = zv[i][kk];
        acc[i][0] += z * w.x; acc[i][1] += z * w.y;
        acc[i][2] += z * w.z; acc[i][3] += z * w.w;
      }
    }
  }

  float4 b = *(const float4*)&B[c0];
  float s[4] = {0.f, 0.f, 0.f, 0.f};
  float s2[4] = {0.f, 0.f, 0.f, 0.f};
#pragma unroll
  for (int i = 0; i < 8; ++i) {
    float4 o;
    o.x = acc[i][0] + b.x; o.y = acc[i][1] + b.y;
    o.z = acc[i][2] + b.z; o.w = acc[i][3] + b.w;
    *(float4*)&Out[(long)(rbase + i) * 128 + c0] = o;
    s[0] += o.x; s[1] += o.y; s[2] += o.z; s[3] += o.w;
    s2[0] += o.x * o.x; s2[1] += o.y * o.y; s2[2] += o.z * o.z; s2[3] += o.w * o.w;
  }
#pragma unroll
  for (int j = 0; j < 4; ++j) {
    atomicAdd(&bnstat[c0 + j], s[j]);
    atomicAdd(&bnstat[128 + c0 + j], s2[j]);
  }
}

// ================= BN apply + relu + final [128x2] matmul =================
__global__ __launch_bounds__(256) void bn_final(
    const float* __restrict__ ZC, const float* __restrict__ bnstat,
    const float* __restrict__ gma, const float* __restrict__ bta,
    const float* __restrict__ W2, const float* __restrict__ B2, float* __restrict__ out)
{
  __shared__ float scl[128], shf[128];
  int tid = threadIdx.x;
  if (tid < 128) {
    float mu = bnstat[tid] * (1.f / NGRAPH);
    float var = bnstat[128 + tid] * (1.f / NGRAPH) - mu * mu;
    float rs = rsqrtf(var + 1e-5f);
    float sc = gma[tid] * rs;
    scl[tid] = sc;
    shf[tid] = bta[tid] - mu * sc;
  }
  __syncthreads();
  int g = blockIdx.x * 256 + tid;
  if (g >= NGRAPH) return;
  float a0 = B2[0], a1 = B2[1];
#pragma unroll 4
  for (int h = 0; h < 128; ++h) {
    float zn = ZC[(long)g * 128 + h] * scl[h] + shf[h];
    zn = fmaxf(zn, 0.f);
    a0 += zn * W2[2 * h];
    a1 += zn * W2[2 * h + 1];
  }
  out[2 * g] = a0;
  out[2 * g + 1] = a1;
}

extern "C" void kernel_launch(void* const* d_in, const int* in_sizes, int n_in,
                              void* d_out, int out_size, void* d_ws, size_t ws_size,
                              hipStream_t stream)
{
  const float* x    = (const float*)d_in[0];
  const int*   ei   = (const int*)d_in[1];
  const int*   batch = (const int*)d_in[3];
  const float* g1w1 = (const float*)d_in[4];  const float* g1b1 = (const float*)d_in[5];
  const float* g1w2 = (const float*)d_in[6];  const float* g1b2 = (const float*)d_in[7];
  const float* g2w1 = (const float*)d_in[8];  const float* g2b1 = (const float*)d_in[9];
  const float* g2w2 = (const float*)d_in[10]; const float* g2b2 = (const float*)d_in[11];
  const float* g3w1 = (const float*)d_in[12]; const float* g3b1 = (const float*)d_in[13];
  const float* g3w2 = (const float*)d_in[14]; const float* g3b2 = (const float*)d_in[15];
  const float* jkw  = (const float*)d_in[16]; const float* jkb  = (const float*)d_in[17];
  const float* c1w  = (const float*)d_in[18]; const float* c1b  = (const float*)d_in[19];
  const float* bng  = (const float*)d_in[20]; const float* bnb  = (const float*)d_in[21];
  const float* c2w  = (const float*)d_in[22]; const float* c2b  = (const float*)d_in[23];

  const int N = in_sizes[3];
  const int E = in_sizes[1] / 2;
  const int* src = ei;
  const int* dst = ei + E;

  char* w = (char*)d_ws;
  auto alloc = [&](size_t bytes) {
    char* p = w;
    w += (bytes + 255) & ~(size_t)255;
    return p;
  };
  _Float16* hA = (_Float16*)alloc((size_t)N * 128 * 2);   // layer-3 out
  _Float16* hB = (_Float16*)alloc((size_t)N * 128 * 2);   // layer-2 out
  _Float16* hC = (_Float16*)alloc((size_t)N * 128 * 2);   // layer-1 out
  _Float16* x8h = (_Float16*)alloc((size_t)N * 8 * 2);
  // P, cnt, bnstat contiguous -> zeroed by prep_hist
  float* P       = (float*)alloc((size_t)NGRAPH * 384 * 4);
  float* cnt     = (float*)alloc((size_t)NGRAPH * 4);
  float* bnstat  = (float*)alloc(256 * 4);
  float* gbuf = (float*)alloc((size_t)NGRAPH * 128 * 4);
  float* zc   = (float*)alloc((size_t)NGRAPH * 128 * 4);
  // deg, scanst contiguous -> one memset (cursor initialized by scan kernel)
  int* deg      = (int*)alloc((size_t)N * 4);
  unsigned* scanst = (unsigned*)alloc((size_t)1024 * 4);
  int* cursor   = (int*)alloc((size_t)N * 4);
  int* rowstart = (int*)alloc((size_t)(N + 1) * 4);
  int* eidx     = (int*)alloc((size_t)E * 4);
  unsigned short* wtbuf = (unsigned short*)alloc((size_t)5 * 2 * 16384 * 2);

  unsigned short* WThi[5];
  unsigned short* WTlo[5];
  for (int m = 0; m < 5; ++m) {
    WThi[m] = wtbuf + (size_t)m * 2 * 16384;
    WTlo[m] = WThi[m] + 16384;
  }

  const int nchunk = (N + 255) / 256;
  const int eb = (E + 255) / 256;

  // ---- memset deg+scanst (contiguous allocs incl. padding) ----
  hipMemsetAsync(deg, 0, (size_t)((char*)(scanst + 1024) - (char*)deg), stream);

  // ---- merged hist + weight prep + x pad(fp16) + zero(P,cnt,bnstat) ----
  {
    WPs p;
    p.w[0] = g1w2; p.w[1] = g2w1; p.w[2] = g2w2; p.w[3] = g3w1; p.w[4] = g3w2;
    for (int m = 0; m < 5; ++m) { p.hi[m] = WThi[m]; p.lo[m] = WTlo[m]; }
    int zeroCount = (NGRAPH * 384 + NGRAPH + 256) / 4;   // float4 count over P..bnstat
    int total = E + 5 * 16384 + N * 8 + zeroCount;
    prep_hist<<<(total + 255) / 256, 256, 0, stream>>>(p, x, x8h, N, dst, deg, E,
                                                       (float4*)P, zeroCount);
  }

  // ---- single-pass scan (writes rowstart + cursor) + fill ----
  scan_onepass<<<nchunk, 256, 0, stream>>>(deg, rowstart, cursor, scanst, N, E, nchunk);
  fill_eidx<<<eb, 256, 0, stream>>>(src, dst, cursor, eidx, E);

  const int fBlocks = (N + 63) / 64;
  const int poolBlocks = (((N + 15) / 16) * 32 + 255) / 256;

  // ---- layers ----
  fused_l1<<<fBlocks, 256, 0, stream>>>(x8h, rowstart, eidx, g1w1, g1b1,
      WThi[0], WTlo[0], g1b2, hC, N);
  fused_gin<<<fBlocks, 256, 0, stream>>>(hC, rowstart, eidx,
      WThi[1], WTlo[1], g2b1, WThi[2], WTlo[2], g2b2, hB, N);
  fused_gin<<<fBlocks, 256, 0, stream>>>(hB, rowstart, eidx,
      WThi[3], WTlo[3], g3b1, WThi[4], WTlo[4], g3b2, hA, N);

  // ---- pooling (all 3 layers, one pass) ----
  pool_all<<<poolBlocks, 256, 0, stream>>>(hC, hB, hA, batch, P, cnt, N);

  // ---- head ----
  jk_gemm<<<NGRAPH / 2, 256, 0, stream>>>(P, cnt, jkw, jkb, gbuf);
  gemm_bn<<<NGRAPH / 64, 256, 0, stream>>>(gbuf, c1w, c1b, zc, bnstat, NGRAPH);
  bn_final<<<(NGRAPH + 255) / 256, 256, 0, stream>>>(zc, bnstat, bng, bnb, c2w, c2b, (float*)d_out);
}

// Round 18
// 410.410 us; speedup vs baseline: 4.5658x; 1.0908x over previous
//
#include <hip/hip_runtime.h>

#define NGRAPH 2048

typedef __attribute__((ext_vector_type(8))) short bf16x8;
typedef __attribute__((ext_vector_type(4))) float f32x4;
typedef __attribute__((ext_vector_type(8))) _Float16 h16x8;
typedef __attribute__((ext_vector_type(2))) _Float16 h16x2;

__device__ inline unsigned short bf16_rne(float f) {
  union { float f; unsigned u; } c; c.f = f;
  unsigned u = c.u + 0x7fffu + ((c.u >> 16) & 1u);
  return (unsigned short)(u >> 16);
}
__device__ inline float bf16_to_f32(unsigned short h) {
  union { float f; unsigned u; } c; c.u = ((unsigned)h) << 16;
  return c.f;
}

// ================= single-pass scan (ticket + decoupled lookback, unsigned flags) =================
__global__ __launch_bounds__(256) void scan_onepass(
    const int* __restrict__ deg, int* __restrict__ rowstart, int* __restrict__ cursor,
    unsigned* __restrict__ scanst, int N, int E, int nchunk)
{
  __shared__ int tmp[256];
  __shared__ int sh_chunk;
  __shared__ int sh_exc;
  int tid = threadIdx.x;
  if (tid == 0) sh_chunk = (int)atomicAdd(&scanst[nchunk], 1u);
  __syncthreads();
  int cb = sh_chunk;
  int i = cb * 256 + tid;
  int v = (i < N) ? deg[i] : 0;
  tmp[tid] = v;
  __syncthreads();
#pragma unroll
  for (int off = 1; off < 256; off <<= 1) {
    int t = (tid >= off) ? tmp[tid - off] : 0;
    __syncthreads();
    tmp[tid] += t;
    __syncthreads();
  }
  int aggregate = tmp[255];

  if (tid == 0) {
    const unsigned VMASK = (1u << 30) - 1u;
    if (cb == 0) {
      atomicExch(&scanst[0], (2u << 30) | (unsigned)aggregate);
      sh_exc = 0;
    } else {
      atomicExch(&scanst[cb], (1u << 30) | (unsigned)aggregate);
      int excv = 0;
      int j = cb - 1;
      while (j >= 0) {
        unsigned s;
        do { s = atomicAdd(&scanst[j], 0u); } while ((s >> 30) == 0u);
        excv += (int)(s & VMASK);
        if ((s >> 30) == 2u) break;
        --j;
      }
      sh_exc = excv;
      atomicExch(&scanst[cb], (2u << 30) | (unsigned)(excv + aggregate));
    }
  }
  __syncthreads();
  int exc = sh_exc;
  if (i < N) {
    int rs = exc + tmp[tid] - v;
    rowstart[i] = rs;
    cursor[i] = rs;
  }
  if (cb == nchunk - 1 && tid == 0) rowstart[N] = E;
}

__global__ __launch_bounds__(256) void fill_eidx(
    const int* __restrict__ src, const int* __restrict__ dst,
    int* __restrict__ cursor, int* __restrict__ eidx, int E)
{
  int e = blockIdx.x * 256 + threadIdx.x;
  if (e >= E) return;
  int d = dst[e];
  int pos = atomicAdd(&cursor[d], 1);
  eidx[pos] = src[e];
}

// ====== merged: degree hist + weight repack + x pad(fp16) + zero(bnstat) + graph boundaries ======
struct WPs {
  const float* w[5];
  unsigned short* hi[5];
  unsigned short* lo[5];
};
__global__ __launch_bounds__(256) void prep_hist(
    WPs p, const float* __restrict__ x, _Float16* __restrict__ x8h, int N,
    const int* __restrict__ dst, int* __restrict__ deg, int E,
    const int* __restrict__ batch, int* __restrict__ gstart,
    float* __restrict__ bnstat)
{
  int g = blockIdx.x * 256 + threadIdx.x;
  if (g < E) {
    atomicAdd(&deg[dst[g]], 1);
    return;
  }
  int q = g - E;
  if (q < 5 * 16384) {
    int m = q >> 14;
    int j = q & 16383;
    int c = j >> 3, e = j & 7;
    int t = c >> 8, kc = (c >> 6) & 3, lane = c & 63;
    int n = t * 16 + (lane & 15);
    int k = kc * 32 + (lane >> 4) * 8 + e;
    float w = p.w[m][k * 128 + n];
    unsigned short h = bf16_rne(w);
    p.hi[m][j] = h;
    p.lo[m][j] = bf16_rne(w - bf16_to_f32(h));
    return;
  }
  q -= 5 * 16384;
  if (q < N * 8) {
    int v = q >> 3, j = q & 7;
    x8h[q] = (_Float16)((j < 7) ? x[(long)v * 7 + j] : 0.f);
    return;
  }
  q -= N * 8;
  if (q < 256) { bnstat[q] = 0.f; return; }
  q -= 256;
  if (q < N) {
    int b = batch[q];
    int bp = (q > 0) ? batch[q - 1] : -1;
    for (int gg = bp + 1; gg <= b; ++gg) gstart[gg] = q;
    if (q == N - 1)
      for (int gg = b + 1; gg <= NGRAPH; ++gg) gstart[gg] = N;
  }
}

// ---- split-precision GEMM pass over a 64x128 fp16 LDS tile (chunk-rot swizzle) ----
__device__ inline void mfma_pass(
    const _Float16* __restrict__ zbuf,
    const unsigned short* __restrict__ Whi, const unsigned short* __restrict__ Wlo,
    int rw, int m16, int quad, int lane, f32x4 acc[8])
{
  int r = rw + m16;
  const _Float16* zrow = &zbuf[r * 128];
#pragma unroll
  for (int kc = 0; kc < 4; ++kc) {
    int cidx = kc * 4 + quad;
    h16x8 zh = *(const h16x8*)&zrow[((cidx + r) & 15) * 8];
    bf16x8 ah, al;
#pragma unroll
    for (int j = 0; j < 8; ++j) {
      float f = (float)zh[j];
      unsigned short h = bf16_rne(f);
      ah[j] = (short)h;
      al[j] = (short)bf16_rne(f - bf16_to_f32(h));
    }
#pragma unroll
    for (int t = 0; t < 8; ++t) {
      long cb = ((t * 4 + kc) * 64 + lane) * 8;
      bf16x8 bh = *(const bf16x8*)&Whi[cb];
      bf16x8 bl = *(const bf16x8*)&Wlo[cb];
      acc[t] = __builtin_amdgcn_mfma_f32_16x16x32_bf16(ah, bh, acc[t], 0, 0, 0);
      acc[t] = __builtin_amdgcn_mfma_f32_16x16x32_bf16(ah, bl, acc[t], 0, 0, 0);
      acc[t] = __builtin_amdgcn_mfma_f32_16x16x32_bf16(al, bh, acc[t], 0, 0, 0);
    }
  }
}

// ================= fused GIN layer (layers 2,3): gather + MLP1 + MLP2 =================
__global__ __launch_bounds__(256, 8) void fused_gin(
    const _Float16* __restrict__ H, const int* __restrict__ rowstart,
    const int* __restrict__ eidx,
    const unsigned short* __restrict__ W1hi, const unsigned short* __restrict__ W1lo,
    const float* __restrict__ B1,
    const unsigned short* __restrict__ W2hi, const unsigned short* __restrict__ W2lo,
    const float* __restrict__ B2,
    _Float16* __restrict__ Out, int M)
{
  __shared__ _Float16 zbuf[64 * 128];   // 16 KB
  int tid = threadIdx.x;
  int rbase = blockIdx.x * 64;

  {
    int sub = tid & 15;
    int ng = tid >> 4;
    const _Float16* Hc = H + sub * 8;
#pragma unroll
    for (int it = 0; it < 4; ++it) {
      int r = it * 16 + ng;
      int v = rbase + r;
      int vc = (v < M) ? v : (M - 1);
      h16x8 sv = *(const h16x8*)&Hc[(long)vc * 128];
      float a0[8], a1[8];
#pragma unroll
      for (int j = 0; j < 8; ++j) { a0[j] = (float)sv[j]; a1[j] = 0.f; }
      int e0 = rowstart[vc], e1 = rowstart[vc + 1];
      int e = e0;
      for (; e + 4 <= e1; e += 4) {
        int s0 = eidx[e], s1 = eidx[e + 1], s2 = eidx[e + 2], s3 = eidx[e + 3];
        h16x8 h0 = *(const h16x8*)&Hc[(long)s0 * 128];
        h16x8 h1 = *(const h16x8*)&Hc[(long)s1 * 128];
        h16x8 h2 = *(const h16x8*)&Hc[(long)s2 * 128];
        h16x8 h3 = *(const h16x8*)&Hc[(long)s3 * 128];
#pragma unroll
        for (int j = 0; j < 8; ++j) {
          a0[j] += (float)h0[j] + (float)h2[j];
          a1[j] += (float)h1[j] + (float)h3[j];
        }
      }
      for (; e + 2 <= e1; e += 2) {
        int s0 = eidx[e], s1 = eidx[e + 1];
        h16x8 h0 = *(const h16x8*)&Hc[(long)s0 * 128];
        h16x8 h1 = *(const h16x8*)&Hc[(long)s1 * 128];
#pragma unroll
        for (int j = 0; j < 8; ++j) {
          a0[j] += (float)h0[j];
          a1[j] += (float)h1[j];
        }
      }
      if (e < e1) {
        int s = eidx[e];
        h16x8 h = *(const h16x8*)&Hc[(long)s * 128];
#pragma unroll
        for (int j = 0; j < 8; ++j) a1[j] += (float)h[j];
      }
      h16x8 zo;
#pragma unroll
      for (int j = 0; j < 8; ++j) zo[j] = (_Float16)(a0[j] + a1[j]);
      *(h16x8*)&zbuf[r * 128 + ((sub + r) & 15) * 8] = zo;
    }
  }
  __syncthreads();

  int lane = tid & 63;
  int wv = tid >> 6;
  int m16 = lane & 15;
  int quad = lane >> 4;
  int rw = wv * 16;

  f32x4 acc[8];
#pragma unroll
  for (int t = 0; t < 8; ++t) acc[t] = (f32x4){0.f, 0.f, 0.f, 0.f};
  mfma_pass(zbuf, W1hi, W1lo, rw, m16, quad, lane, acc);

  float bias[8];
#pragma unroll
  for (int t = 0; t < 8; ++t) bias[t] = B1[t * 16 + m16];

  __syncthreads();
#pragma unroll
  for (int i = 0; i < 4; ++i) {
    int r = rw + quad * 4 + i;
#pragma unroll
    for (int t = 0; t < 8; ++t) {
      int col = t * 16 + m16;
      int cidx = col >> 3;
      zbuf[r * 128 + ((cidx + r) & 15) * 8 + (col & 7)] =
          (_Float16)fmaxf(acc[t][i] + bias[t], 0.f);
    }
  }
  __syncthreads();

#pragma unroll
  for (int t = 0; t < 8; ++t) acc[t] = (f32x4){0.f, 0.f, 0.f, 0.f};
  mfma_pass(zbuf, W2hi, W2lo, rw, m16, quad, lane, acc);

#pragma unroll
  for (int t = 0; t < 8; ++t) bias[t] = B2[t * 16 + m16];

#pragma unroll
  for (int i = 0; i < 4; ++i) {
    int r = rbase + rw + quad * 4 + i;
    if (r < M) {
#pragma unroll
      for (int t = 0; t < 8; ++t) {
        float o = fmaxf(acc[t][i] + bias[t], 0.f);
        Out[(long)r * 128 + t * 16 + m16] = (_Float16)o;
      }
    }
  }
}

// ================= fused layer 1: gather(x8h fp16) + K=7 GEMM + MFMA GEMM =================
__global__ __launch_bounds__(256, 8) void fused_l1(
    const _Float16* __restrict__ x8h, const int* __restrict__ rowstart,
    const int* __restrict__ eidx,
    const float* __restrict__ W1, const float* __restrict__ B1,
    const unsigned short* __restrict__ W2hi, const unsigned short* __restrict__ W2lo,
    const float* __restrict__ B2, _Float16* __restrict__ Out, int M)
{
  __shared__ _Float16 ybuf[64 * 128];
  __shared__ float z1s[64][8];
  int tid = threadIdx.x;
  int rbase = blockIdx.x * 64;

  {
    int node = tid >> 2, sub = tid & 3;
    int v = rbase + node;
    int vc = (v < M) ? v : (M - 1);
    float a[8];
    if (sub == 0) {
      h16x8 sv = *(const h16x8*)&x8h[(long)vc * 8];
#pragma unroll
      for (int j = 0; j < 8; ++j) a[j] = (float)sv[j];
    } else {
#pragma unroll
      for (int j = 0; j < 8; ++j) a[j] = 0.f;
    }
    int e0 = rowstart[vc], e1 = rowstart[vc + 1];
    int e = e0 + sub;
    for (; e + 4 < e1; e += 8) {
      int s0 = eidx[e], s1 = eidx[e + 4];
      h16x8 h0 = *(const h16x8*)&x8h[(long)s0 * 8];
      h16x8 h1 = *(const h16x8*)&x8h[(long)s1 * 8];
#pragma unroll
      for (int j = 0; j < 8; ++j) a[j] += (float)h0[j] + (float)h1[j];
    }
    if (e < e1) {
      int s = eidx[e];
      h16x8 h = *(const h16x8*)&x8h[(long)s * 8];
#pragma unroll
      for (int j = 0; j < 8; ++j) a[j] += (float)h[j];
    }
#pragma unroll
    for (int j = 0; j < 8; ++j) {
      a[j] += __shfl_xor(a[j], 1, 64);
      a[j] += __shfl_xor(a[j], 2, 64);
    }
    if (sub == 0) {
#pragma unroll
      for (int j = 0; j < 8; ++j) z1s[node][j] = a[j];
    }
  }
  __syncthreads();

  {
    int c = tid & 127;
    int cidx = c >> 3, celt = c & 7;
    int rh0 = (tid >> 7) * 32;
    float w1r[7];
#pragma unroll
    for (int k = 0; k < 7; ++k) w1r[k] = W1[k * 128 + c];
    float b1 = B1[c];
#pragma unroll 4
    for (int rr = 0; rr < 32; ++rr) {
      int r = rh0 + rr;
      const float* zp = z1s[r];
      float a = b1;
#pragma unroll
      for (int k = 0; k < 7; ++k) a += zp[k] * w1r[k];
      ybuf[r * 128 + ((cidx + r) & 15) * 8 + celt] = (_Float16)fmaxf(a, 0.f);
    }
  }
  __syncthreads();

  int lane = tid & 63;
  int wv = tid >> 6;
  int m16 = lane & 15;
  int quad = lane >> 4;
  int rw = wv * 16;

  f32x4 acc[8];
#pragma unroll
  for (int t = 0; t < 8; ++t) acc[t] = (f32x4){0.f, 0.f, 0.f, 0.f};
  mfma_pass(ybuf, W2hi, W2lo, rw, m16, quad, lane, acc);

  float bias[8];
#pragma unroll
  for (int t = 0; t < 8; ++t) bias[t] = B2[t * 16 + m16];

#pragma unroll
  for (int i = 0; i < 4; ++i) {
    int r = rbase + rw + quad * 4 + i;
    if (r < M) {
#pragma unroll
      for (int t = 0; t < 8; ++t) {
        float o = fmaxf(acc[t][i] + bias[t], 0.f);
        Out[(long)r * 128 + t * 16 + m16] = (_Float16)o;
      }
    }
  }
}

// ================= pooling: one block per graph, zero atomics =================
// thread t < 192 owns column pair cp = 2t of the 384 concatenated columns.
__global__ __launch_bounds__(256) void pool_direct(
    const _Float16* __restrict__ H1, const _Float16* __restrict__ H2,
    const _Float16* __restrict__ H3, const int* __restrict__ gstart,
    float* __restrict__ P, float* __restrict__ cnt)
{
  int g = blockIdx.x;
  int s = gstart[g], e = gstart[g + 1];
  int tid = threadIdx.x;
  if (tid == 0) cnt[g] = (float)(e - s);
  if (tid >= 192) return;
  int cp = tid * 2;
  const _Float16* A = (cp < 128) ? H1 : ((cp < 256) ? H2 : H3);
  int c = cp & 127;
  float ax = 0.f, ay = 0.f, bx = 0.f, by = 0.f;
  int i = s;
  for (; i + 2 <= e; i += 2) {
    h16x2 v0 = *(const h16x2*)&A[(long)i * 128 + c];
    h16x2 v1 = *(const h16x2*)&A[(long)(i + 1) * 128 + c];
    ax += (float)v0[0]; ay += (float)v0[1];
    bx += (float)v1[0]; by += (float)v1[1];
  }
  if (i < e) {
    h16x2 v0 = *(const h16x2*)&A[(long)i * 128 + c];
    ax += (float)v0[0]; ay += (float)v0[1];
  }
  float2 o = {ax + bx, ay + by};
  *(float2*)&P[(long)g * 384 + cp] = o;
}

// ================= JK: G = P(2048x384) @ W(384x128) + cnt*B  (1024 blocks) =================
__global__ __launch_bounds__(256) void jk_gemm(
    const float* __restrict__ P, const float* __restrict__ cnt,
    const float* __restrict__ W, const float* __restrict__ B,
    float* __restrict__ G)
{
  __shared__ float pl[768];
  int tid = threadIdx.x, blk = blockIdx.x;
  for (int o = tid; o < 768; o += 256) pl[o] = P[(long)blk * 768 + o];
  __syncthreads();
  int rr = tid >> 7;
  int col = tid & 127;
  int row = blk * 2 + rr;
  float acc = cnt[row] * B[col];
#pragma unroll 8
  for (int k = 0; k < 384; ++k)
    acc += pl[rr * 384 + k] * W[k * 128 + col];
  G[(long)row * 128 + col] = acc;
}

// ================= classifier GEMM + BN stat atomics =================
__global__ __launch_bounds__(256) void gemm_bn(
    const float* __restrict__ Z,
    const float* __restrict__ W, const float* __restrict__ B,
    float* __restrict__ Out, float* __restrict__ bnstat, int M)
{
  __shared__ float wlds[128 * 128];
  int tid = threadIdx.x;
  {
    const float4* Ws = (const float4*)W;
    float4* Wd = (float4*)wlds;
#pragma unroll
    for (int i = 0; i < 16; ++i) Wd[i * 256 + tid] = Ws[i * 256 + tid];
  }
  __syncthreads();

  int rg = tid >> 5;
  int c0 = (tid & 31) * 4;
  int rbase = blockIdx.x * 64 + rg * 8;

  float acc[8][4];
#pragma unroll
  for (int i = 0; i < 8; ++i)
#pragma unroll
    for (int j = 0; j < 4; ++j) acc[i][j] = 0.f;

#pragma unroll 2
  for (int kc = 0; kc < 128; kc += 4) {
    float zv[8][4];
#pragma unroll
    for (int i = 0; i < 8; ++i) {
      float4 z = *(const float4*)&Z[(long)(rbase + i) * 128 + kc];
      zv[i][0] = z.x; zv[i][1] = z.y; zv[i][2] = z.z; zv[i][3] = z.w;
    }
#pragma unroll
    for (int kk = 0; kk < 4; ++kk) {
      float4 w = *(const float4*)&wlds[(kc + kk) * 128 + c0];
#pragma unroll
      for (int i = 0; i < 8; ++i) {
        float z = zv[i][kk];
        acc[i][0] += z * w.x; acc[i][1] += z * w.y;
        acc[i][2] += z * w.z; acc[i][3] += z * w.w;
      }
    }
  }

  float4 b = *(const float4*)&B[c0];
  float s[4] = {0.f, 0.f, 0.f, 0.f};
  float s2[4] = {0.f, 0.f, 0.f, 0.f};
#pragma unroll
  for (int i = 0; i < 8; ++i) {
    float4 o;
    o.x = acc[i][0] + b.x; o.y = acc[i][1] + b.y;
    o.z = acc[i][2] + b.z; o.w = acc[i][3] + b.w;
    *(float4*)&Out[(long)(rbase + i) * 128 + c0] = o;
    s[0] += o.x; s[1] += o.y; s[2] += o.z; s[3] += o.w;
    s2[0] += o.x * o.x; s2[1] += o.y * o.y; s2[2] += o.z * o.z; s2[3] += o.w * o.w;
  }
#pragma unroll
  for (int j = 0; j < 4; ++j) {
    atomicAdd(&bnstat[c0 + j], s[j]);
    atomicAdd(&bnstat[128 + c0 + j], s2[j]);
  }
}

// ================= BN apply + relu + final [128x2] matmul =================
__global__ __launch_bounds__(256) void bn_final(
    const float* __restrict__ ZC, const float* __restrict__ bnstat,
    const float* __restrict__ gma, const float* __restrict__ bta,
    const float* __restrict__ W2, const float* __restrict__ B2, float* __restrict__ out)
{
  __shared__ float scl[128], shf[128];
  int tid = threadIdx.x;
  if (tid < 128) {
    float mu = bnstat[tid] * (1.f / NGRAPH);
    float var = bnstat[128 + tid] * (1.f / NGRAPH) - mu * mu;
    float rs = rsqrtf(var + 1e-5f);
    float sc = gma[tid] * rs;
    scl[tid] = sc;
    shf[tid] = bta[tid] - mu * sc;
  }
  __syncthreads();
  int g = blockIdx.x * 256 + tid;
  if (g >= NGRAPH) return;
  float a0 = B2[0], a1 = B2[1];
#pragma unroll 4
  for (int h = 0; h < 128; ++h) {
    float zn = ZC[(long)g * 128 + h] * scl[h] + shf[h];
    zn = fmaxf(zn, 0.f);
    a0 += zn * W2[2 * h];
    a1 += zn * W2[2 * h + 1];
  }
  out[2 * g] = a0;
  out[2 * g + 1] = a1;
}

extern "C" void kernel_launch(void* const* d_in, const int* in_sizes, int n_in,
                              void* d_out, int out_size, void* d_ws, size_t ws_size,
                              hipStream_t stream)
{
  const float* x    = (const float*)d_in[0];
  const int*   ei   = (const int*)d_in[1];
  const int*   batch = (const int*)d_in[3];
  const float* g1w1 = (const float*)d_in[4];  const float* g1b1 = (const float*)d_in[5];
  const float* g1w2 = (const float*)d_in[6];  const float* g1b2 = (const float*)d_in[7];
  const float* g2w1 = (const float*)d_in[8];  const float* g2b1 = (const float*)d_in[9];
  const float* g2w2 = (const float*)d_in[10]; const float* g2b2 = (const float*)d_in[11];
  const float* g3w1 = (const float*)d_in[12]; const float* g3b1 = (const float*)d_in[13];
  const float* g3w2 = (const float*)d_in[14]; const float* g3b2 = (const float*)d_in[15];
  const float* jkw  = (const float*)d_in[16]; const float* jkb  = (const float*)d_in[17];
  const float* c1w  = (const float*)d_in[18]; const float* c1b  = (const float*)d_in[19];
  const float* bng  = (const float*)d_in[20]; const float* bnb  = (const float*)d_in[21];
  const float* c2w  = (const float*)d_in[22]; const float* c2b  = (const float*)d_in[23];

  const int N = in_sizes[3];
  const int E = in_sizes[1] / 2;
  const int* src = ei;
  const int* dst = ei + E;

  char* w = (char*)d_ws;
  auto alloc = [&](size_t bytes) {
    char* p = w;
    w += (bytes + 255) & ~(size_t)255;
    return p;
  };
  _Float16* hA = (_Float16*)alloc((size_t)N * 128 * 2);   // layer-3 out
  _Float16* hB = (_Float16*)alloc((size_t)N * 128 * 2);   // layer-2 out
  _Float16* hC = (_Float16*)alloc((size_t)N * 128 * 2);   // layer-1 out
  _Float16* x8h = (_Float16*)alloc((size_t)N * 8 * 2);
  float* P       = (float*)alloc((size_t)NGRAPH * 384 * 4);
  float* cnt     = (float*)alloc((size_t)NGRAPH * 4);
  float* bnstat  = (float*)alloc(256 * 4);
  float* gbuf = (float*)alloc((size_t)NGRAPH * 128 * 4);
  float* zc   = (float*)alloc((size_t)NGRAPH * 128 * 4);
  // deg, scanst contiguous -> one memset
  int* deg      = (int*)alloc((size_t)N * 4);
  unsigned* scanst = (unsigned*)alloc((size_t)1024 * 4);
  int* cursor   = (int*)alloc((size_t)N * 4);
  int* rowstart = (int*)alloc((size_t)(N + 1) * 4);
  int* eidx     = (int*)alloc((size_t)E * 4);
  int* gstart   = (int*)alloc((size_t)(NGRAPH + 1) * 4);
  unsigned short* wtbuf = (unsigned short*)alloc((size_t)5 * 2 * 16384 * 2);

  unsigned short* WThi[5];
  unsigned short* WTlo[5];
  for (int m = 0; m < 5; ++m) {
    WThi[m] = wtbuf + (size_t)m * 2 * 16384;
    WTlo[m] = WThi[m] + 16384;
  }

  const int nchunk = (N + 255) / 256;
  const int eb = (E + 255) / 256;

  // ---- memset deg+scanst (contiguous allocs incl. padding) ----
  hipMemsetAsync(deg, 0, (size_t)((char*)(scanst + 1024) - (char*)deg), stream);

  // ---- merged hist + weight prep + x pad(fp16) + zero(bnstat) + graph boundaries ----
  {
    WPs p;
    p.w[0] = g1w2; p.w[1] = g2w1; p.w[2] = g2w2; p.w[3] = g3w1; p.w[4] = g3w2;
    for (int m = 0; m < 5; ++m) { p.hi[m] = WThi[m]; p.lo[m] = WTlo[m]; }
    int total = E + 5 * 16384 + N * 8 + 256 + N;
    prep_hist<<<(total + 255) / 256, 256, 0, stream>>>(p, x, x8h, N, dst, deg, E,
                                                       batch, gstart, bnstat);
  }

  // ---- single-pass scan (writes rowstart + cursor) + fill ----
  scan_onepass<<<nchunk, 256, 0, stream>>>(deg, rowstart, cursor, scanst, N, E, nchunk);
  fill_eidx<<<eb, 256, 0, stream>>>(src, dst, cursor, eidx, E);

  const int fBlocks = (N + 63) / 64;

  // ---- layers ----
  fused_l1<<<fBlocks, 256, 0, stream>>>(x8h, rowstart, eidx, g1w1, g1b1,
      WThi[0], WTlo[0], g1b2, hC, N);
  fused_gin<<<fBlocks, 256, 0, stream>>>(hC, rowstart, eidx,
      WThi[1], WTlo[1], g2b1, WThi[2], WTlo[2], g2b2, hB, N);
  fused_gin<<<fBlocks, 256, 0, stream>>>(hB, rowstart, eidx,
      WThi[3], WTlo[3], g3b1, WThi[4], WTlo[4], g3b2, hA, N);

  // ---- pooling: one block per graph, no atomics ----
  pool_direct<<<NGRAPH, 256, 0, stream>>>(hC, hB, hA, gstart, P, cnt);

  // ---- head ----
  jk_gemm<<<NGRAPH / 2, 256, 0, stream>>>(P, cnt, jkw, jkb, gbuf);
  gemm_bn<<<NGRAPH / 64, 256, 0, stream>>>(gbuf, c1w, c1b, zc, bnstat, NGRAPH);
  bn_final<<<(NGRAPH + 255) / 256, 256, 0, stream>>>(zc, bnstat, bng, bnb, c2w, c2b, (float*)d_out);
}